// Round 12
// baseline (1998.644 us; speedup 1.0000x reference)
//
#include <hip/hip_runtime.h>
#include <hip/hip_bf16.h>
#include <math.h>

#define N_PTS 15872
#define M_PTS 35637
#define KNN_K 5
#define KUP   20
#define UP_ROWS (M_PTS * KUP)   // 712740
#define NTILE (N_PTS/32)        // 496 i/j tiles
#define N_EDGE (N_PTS*KNN_K)    // 79360
#define CDIV(a,b) (((a)+(b)-1)/(b))
#define INV2PI 0.15915494309189535f

typedef __hip_bfloat16 bf16;
typedef unsigned int uint;
typedef unsigned short ushort_t;
__device__ __forceinline__ float b2f(bf16 x){ return __bfloat162float(x); }

// round-to-nearest-even fp32 -> bf16 bit pattern (finite inputs)
__device__ __forceinline__ uint f2bf_bits(float x){
  uint u = __float_as_uint(x);
  return (u + 0x7FFFu + ((u>>16)&1u)) >> 16;
}

// fp32 -> fp16 bits (RNE via hardware cvt)
__device__ __forceinline__ ushort_t f2h_bits(float x){
  union { _Float16 h; ushort_t u; } c; c.h = (_Float16)x; return c.u;
}

// sin with input in REVOLUTIONS (v_sin_f32 semantics); weights/biases are
// pre-scaled by 1/2pi so this is a single VALU op.
__device__ __forceinline__ float sinrev(float x){
#if __has_builtin(__builtin_amdgcn_sinf)
  return __builtin_amdgcn_sinf(x);
#else
  return __sinf(x * 6.283185307179586f);
#endif
}

typedef __attribute__((ext_vector_type(8))) short bf16x8;
typedef __attribute__((ext_vector_type(8))) _Float16 f16x8;
typedef __attribute__((ext_vector_type(2))) __fp16 fp16x2_t;
typedef __attribute__((ext_vector_type(16))) float f32x16;
union FragAB { bf16x8 v; uint u[4]; };
union FragB  { bf16x8 v; uint4 q; };
union FragH  { f16x8 v; uint4 q; _Float16 h[8]; };
union Acc16  { f32x16 v; float f[16]; };
union H2U    { fp16x2_t h; uint u; };

// ---------------------------------------------------------------------------
__global__ void flag_k(const uint* __restrict__ pos_raw, int* __restrict__ flag){
  if (threadIdx.x == 0 && blockIdx.x == 0)
    flag[0] = (pos_raw[0] == 0x3F800000u) ? 1 : 0;
}

struct CvtTab { const void* src[52]; int start[52]; };
__global__ __launch_bounds__(256) void cvt_all_k(CvtTab tab, float* __restrict__ dst,
                                                 const int* __restrict__ flag, int total){
  int i = blockIdx.x*256 + threadIdx.x;
  if (i >= total) return;
  int s = 0;
#pragma unroll 1
  for (int k = 1; k < 52; k++) if (tab.start[k] <= i) s = k;
  int off = i - tab.start[s];
  float v = flag[0] ? b2f(((const bf16*)tab.src[s])[off]) : ((const float*)tab.src[s])[off];
  dst[i] = v;
}

// pack SIREN 128x128 weights into frag-major fp16 plane; per-layer output
// scale AND 1/2pi folded in (epilogue uses raw v_sin on revolutions).
// sigma-fold: store W[n][sigma(k)] at physical slot k so the consuming
// lane's next-layer B-frag assembles from its OWN registers.
__global__ void packfrag16_k(const float* __restrict__ w, const float* __restrict__ sr,
                             ushort_t* __restrict__ out, int n){
  int i = blockIdx.x*256 + threadIdx.x;
  if (i >= n) return;
  int j = i & 7;
  int lam = (i >> 3) & 63;
  int fg = i >> 9;
  int t = fg & 3, ks = (fg >> 2) & 1, Q = (fg >> 3) & 3, l = fg >> 5;
  int nn = t*32 + (lam & 31);
  int kk = Q*32 + ks*16 + ((j>>2)<<3) + ((lam>>5)<<2) + (j&3);   // sigma-fold
  float x = w[l*16384 + nn*128 + kk] * sr[l*128 + nn] * INV2PI;
  out[i] = f2h_bits(x);
}

// batched frag-major split-bf16 pack for all 18 weight matrices in ONE launch.
struct PackTab { const float* src[18]; int N[18], K[18], ldk[18], Kpad[18], start[18]; };
__global__ __launch_bounds__(256) void packw_all_k(PackTab t, ushort_t* __restrict__ whi,
                                                   ushort_t* __restrict__ wlo, int total){
  int i = blockIdx.x*256 + threadIdx.x;
  if (i >= total) return;
  int s = 0;
#pragma unroll 1
  for (int q = 1; q < 18; q++) if (t.start[q] <= i) s = q;
  int ii = i - t.start[s];
  int j = ii & 7;
  int lane = (ii >> 3) & 63;
  int fr = ii >> 9;
  int nq = t.Kpad[s] >> 5;
  int ks = fr & 1;
  int q  = (fr >> 1) % nq;
  int nt = (fr >> 1) / nq;
  int n = nt*32 + (lane & 31);
  int k = q*32 + ks*16 + (lane >> 5)*8 + j;
  float x = (n < t.N[s] && k < t.K[s]) ? t.src[s][(size_t)n*t.ldk[s] + k] : 0.f;
  uint hb = f2bf_bits(x);
  uint lb = f2bf_bits(x - __uint_as_float(hb << 16));
  whi[i] = (ushort_t)hb;
  wlo[i] = (ushort_t)lb;
}

// pack KNN features into frag-major split-bf16 planes with norm augmentation.
__global__ void packknn_k(const float* __restrict__ xf, const float* __restrict__ nr,
                          ushort_t* __restrict__ ahi, ushort_t* __restrict__ alo,
                          ushort_t* __restrict__ bhi, ushort_t* __restrict__ blo){
  int i = blockIdx.x*256 + threadIdx.x;
  if (i >= NTILE*5*64*8) return;
  int e = i & 7;
  int lane = (i >> 3) & 63;
  int rest = i >> 9;
  int kc = rest % 5, jt = rest / 5;
  int n = jt*32 + (lane & 31);
  int k = kc*16 + (lane >> 5)*8 + e;
  float f = (k < 64) ? xf[(size_t)n*227 + 35 + k] : 0.f;
  float av, bv;
  if (k < 64)      { av = 2.f*f;   bv = f; }
  else if (k == 64){ av = nr[n];   bv = -1.f; }
  else if (k == 65){ av = 1.f;     bv = -nr[n]; }
  else             { av = 0.f;     bv = 0.f; }
  uint ah = f2bf_bits(av); uint al = f2bf_bits(av - __uint_as_float(ah<<16));
  uint bh = f2bf_bits(bv); uint bl = f2bf_bits(bv - __uint_as_float(bh<<16));
  ahi[i] = (ushort_t)ah; alo[i] = (ushort_t)al;
  bhi[i] = (ushort_t)bh; blo[i] = (ushort_t)bl;
}

__global__ void fillmark_k(bf16* __restrict__ out, int n){
  int i = blockIdx.x*256 + threadIdx.x;
  if (i < n) out[i] = __float2bfloat16(12345.0f);
}

// ---------------------------------------------------------------------------
// Single-layer split-bf16 MFMA GEMM (validated round 8): 128-col panels,
// acc[2], K-chunked 32 KB slab. Used for fc1's 192->384 and 384->256.
// ---------------------------------------------------------------------------
template<int ACT>
__global__ __launch_bounds__(256) void gemm_mfma_k(
    const float* __restrict__ A, int lda, int K, int M,
    const ushort_t* __restrict__ wh, const ushort_t* __restrict__ wl,
    int woff, int KqTot,
    const float* __restrict__ scale, const float* __restrict__ shift,
    float* __restrict__ C, int ldc, int N)
{
  __shared__ __align__(16) uint slab[64*128];   // 32768 B
  const int tid = threadIdx.x;
  const int lane = tid & 63;
  const int wv = tid >> 6;
  const int np = lane & 31;
  const int hb2 = lane >> 5;
  const int rhalf = wv & 1, thalf = wv >> 1;
  const int rb = blockIdx.x * 64;
  const int tbase = blockIdx.y * 4;
  const int row_l = rhalf*32 + np;
  int NtLoc = (N >> 5) - tbase; if (NtLoc > 4) NtLoc = 4;

  Acc16 acc[2];
#pragma unroll
  for (int u=0;u<2;u++)
#pragma unroll
    for (int i=0;i<16;i++) acc[u].f[i] = 0.f;

#pragma unroll 1
  for (int k0 = 0; k0 < K; k0 += 128) {
    for (int e = tid; e < 64*32; e += 256) {
      int r = e >> 5, g = e & 31;
      int gr = rb + r;
      uint p[4];
#pragma unroll
      for (int u=0;u<4;u++){
        int k = k0 + g*4 + u;
        float f = (gr < M && k < K) ? A[(size_t)gr*lda + k] : 0.f;
        uint hb = f2bf_bits(f);
        uint lb = f2bf_bits(f - __uint_as_float(hb<<16));
        p[u] = (hb<<16) | lb;
      }
      *(uint4*)&slab[r*128 + (((g ^ r) & 31)<<2)] = make_uint4(p[0],p[1],p[2],p[3]);
    }
    __syncthreads();
    int qb = k0 >> 5;
    int KqLoc = KqTot - qb; if (KqLoc > 4) KqLoc = 4;
#pragma unroll 1
    for (int q = 0; q < KqLoc; q++){
#pragma unroll
      for (int ks = 0; ks < 2; ks++){
        int g0 = q*8 + ks*4 + hb2*2;
        uint4 a0 = *(const uint4*)&slab[row_l*128 + ((((g0  ) ^ row_l) & 31)<<2)];
        uint4 a1 = *(const uint4*)&slab[row_l*128 + ((((g0+1) ^ row_l) & 31)<<2)];
        uint au[8] = {a0.x,a0.y,a0.z,a0.w,a1.x,a1.y,a1.z,a1.w};
        FragAB ah, al;
#pragma unroll
        for (int p=0;p<4;p++){
          ah.u[p] = (au[2*p]>>16)     | (au[2*p+1] & 0xFFFF0000u);
          al.u[p] = (au[2*p]&0xFFFFu) | (au[2*p+1]<<16);
        }
#pragma unroll
        for (int u=0;u<2;u++){
          int t = thalf + u*2;
          if (t < NtLoc){
            size_t fb = (size_t)woff + ((size_t)(((tbase+t)*KqTot + qb + q)*2 + ks))*512 + (size_t)lane*8;
            FragB bh, bl;
            bh.q = *(const uint4*)(wh + fb);
            bl.q = *(const uint4*)(wl + fb);
            acc[u].v = __builtin_amdgcn_mfma_f32_32x32x16_bf16(ah.v, bh.v, acc[u].v, 0,0,0);
            acc[u].v = __builtin_amdgcn_mfma_f32_32x32x16_bf16(al.v, bh.v, acc[u].v, 0,0,0);
            acc[u].v = __builtin_amdgcn_mfma_f32_32x32x16_bf16(ah.v, bl.v, acc[u].v, 0,0,0);
          }
        }
      }
    }
    __syncthreads();
  }

#pragma unroll
  for (int u=0;u<2;u++){
    int t = thalf + u*2;
    if (t < NtLoc){
      int col = (tbase+t)*32 + np;
      float scv = scale[col], shv = shift[col];
#pragma unroll
      for (int reg=0;reg<16;reg++){
        int r32 = (reg&3) + 8*(reg>>2) + 4*hb2;
        int gr = rb + rhalf*32 + r32;
        if (gr < M){
          float v = acc[u].f[reg]*scv + shv;
          if (ACT==1) v = v > 0.f ? v : 0.2f*v;
          C[(size_t)gr*ldc + col] = v;
        }
      }
    }
  }
}

// ---------------------------------------------------------------------------
// Generic fused per-row MLP (validated round 9): up to 6 layers, dims <= 256.
// ---------------------------------------------------------------------------
struct MLayer { int K, N, Kq, Nt, woff, soff, hoff, epi, act; float gmul; };
struct MCfg { MLayer L[6]; };

template<int NL, int OUTMODE>
__global__ __launch_bounds__(256) void mlp_fused_k(
    const float* __restrict__ A0, int lda0, int K0, int M,
    MCfg cfg,
    const ushort_t* __restrict__ wh, const ushort_t* __restrict__ wl,
    const float* __restrict__ wc,
    float* __restrict__ Cout, int ldc,
    void* __restrict__ oflg, const int* __restrict__ flag)
{
  __shared__ __align__(16) uint slab[64*256];   // 65536 B
  const int tid = threadIdx.x;
  const int lane = tid & 63;
  const int wv = tid >> 6;
  const int np = lane & 31;
  const int hb2 = lane >> 5;
  const int rhalf = wv & 1, thalf = wv >> 1;
  const int rb = blockIdx.x * 64;
  const int row_l = rhalf*32 + np;

  for (int e = tid; e < 64*64; e += 256) {
    int r = e >> 6, g = e & 63;
    int gr = rb + r;
    uint p[4];
#pragma unroll
    for (int u=0;u<4;u++){
      int k = g*4+u;
      float f = (gr < M && k < K0) ? A0[(size_t)gr*lda0 + k] : 0.f;
      uint hb = f2bf_bits(f);
      uint lb = f2bf_bits(f - __uint_as_float(hb<<16));
      p[u] = (hb<<16) | lb;
    }
    *(uint4*)&slab[r*256 + (((g ^ r) & 63)<<2)] = make_uint4(p[0],p[1],p[2],p[3]);
  }
  __syncthreads();

#pragma unroll 1
  for (int l = 0; l < NL; l++){
    const int N = cfg.L[l].N, Kq = cfg.L[l].Kq, Nt = cfg.L[l].Nt;
    const int woff = cfg.L[l].woff, soff = cfg.L[l].soff, hoff = cfg.L[l].hoff;
    const int epi = cfg.L[l].epi, actf = cfg.L[l].act;
    const float gmul = cfg.L[l].gmul;
    Acc16 acc[4];
#pragma unroll
    for (int u=0;u<4;u++)
#pragma unroll
      for (int i=0;i<16;i++) acc[u].f[i] = 0.f;

#pragma unroll 1
    for (int q = 0; q < Kq; q++){
#pragma unroll
      for (int ks = 0; ks < 2; ks++){
        int g0 = (q*32 + ks*16 + hb2*8) >> 2;
        uint4 a0 = *(const uint4*)&slab[row_l*256 + ((((g0  ) ^ row_l) & 63)<<2)];
        uint4 a1 = *(const uint4*)&slab[row_l*256 + ((((g0+1) ^ row_l) & 63)<<2)];
        uint au[8] = {a0.x,a0.y,a0.z,a0.w,a1.x,a1.y,a1.z,a1.w};
        FragAB ah, al;
#pragma unroll
        for (int p=0;p<4;p++){
          ah.u[p] = (au[2*p]>>16)     | (au[2*p+1] & 0xFFFF0000u);
          al.u[p] = (au[2*p]&0xFFFFu) | (au[2*p+1]<<16);
        }
#pragma unroll
        for (int u=0;u<4;u++){
          int t = thalf + u*2;
          if (t < Nt){
            size_t fb = (size_t)woff + ((size_t)((t*Kq + q)*2 + ks))*512 + (size_t)lane*8;
            FragB bh, bl;
            bh.q = *(const uint4*)(wh + fb);
            bl.q = *(const uint4*)(wl + fb);
            acc[u].v = __builtin_amdgcn_mfma_f32_32x32x16_bf16(ah.v, bh.v, acc[u].v, 0,0,0);
            acc[u].v = __builtin_amdgcn_mfma_f32_32x32x16_bf16(al.v, bh.v, acc[u].v, 0,0,0);
            acc[u].v = __builtin_amdgcn_mfma_f32_32x32x16_bf16(ah.v, bl.v, acc[u].v, 0,0,0);
          }
        }
      }
    }
    __syncthreads();
#pragma unroll
    for (int u=0;u<4;u++){
      int t = thalf + u*2;
      if (t < Nt){
        int col = t*32 + np;
        if (col < N){
          float scv = (epi==0) ? wc[soff+col] : 0.f;
          float shv = wc[hoff+col];
#pragma unroll
          for (int reg=0;reg<16;reg++){
            int r32 = (reg&3) + 8*(reg>>2) + 4*hb2;
            float v = acc[u].f[reg];
            if (epi==0)      v = v*scv + shv;
            else if (epi==1) v = v + shv;
            else             v = (v + shv)*gmul;
            if (actf==1)      v = v > 0.f ? v : 0.2f*v;
            else if (actf==2) v = __sinf(v);
            if (l == NL-1){
              int gr = rb + rhalf*32 + r32;
              if (gr < M){
                if (OUTMODE==0) Cout[(size_t)gr*ldc + col] = v;
                else {
                  if (!(fabsf(v) < 1e30f)) v = 777.0f;  // canary
                  size_t oi = (size_t)gr*3 + col;
                  if (flag[0]) ((bf16*)oflg)[oi] = __float2bfloat16(v);
                  else         ((float*)oflg)[oi] = v;
                }
              }
            } else {
              int r = rhalf*32 + r32;
              uint hb = f2bf_bits(v);
              uint lb = f2bf_bits(v - __uint_as_float(hb<<16));
              slab[r*256 + ((((col>>2) ^ r) & 63)<<2) + (col&3)] = (hb<<16) | lb;
            }
          }
        }
      }
    }
    __syncthreads();
  }
}

// ---------------------------------------------------------------------------
// Edge-conv MLP with FUSED GATHER staging (round 12): stages
// cat(xf[j]-xf[n], xf[n]) directly from x_feat using the knn index — no
// intermediate edge buffer. Compute/epilogue identical to mlp_fused (OUT=0).
// ---------------------------------------------------------------------------
template<int NL>
__global__ __launch_bounds__(256) void mlp_edge_k(
    const float* __restrict__ xf, int coff, int CIN,
    const int* __restrict__ idx, int n0, int M /*edges*/,
    MCfg cfg,
    const ushort_t* __restrict__ wh, const ushort_t* __restrict__ wl,
    const float* __restrict__ wc,
    float* __restrict__ Cout, int ldc)
{
  __shared__ __align__(16) uint slab[64*256];   // 65536 B
  const int tid = threadIdx.x;
  const int lane = tid & 63;
  const int wv = tid >> 6;
  const int np = lane & 31;
  const int hb2 = lane >> 5;
  const int rhalf = wv & 1, thalf = wv >> 1;
  const int rb = blockIdx.x * 64;
  const int row_l = rhalf*32 + np;
  const int W2 = 2*CIN;

  for (int e = tid; e < 64*64; e += 256) {
    int r = e >> 6, g = e & 63;
    int ek = rb + r;
    int n = 0, j = 0;
    bool ok = (ek < M);
    if (ok){
      n = n0 + ek/KNN_K;
      j = idx[n*KNN_K + ek%KNN_K];
    }
    uint p[4];
#pragma unroll
    for (int u=0;u<4;u++){
      int k = g*4+u;
      float f = 0.f;
      if (ok && k < W2){
        f = (k < CIN) ? xf[(size_t)j*227 + coff + k] - xf[(size_t)n*227 + coff + k]
                      : xf[(size_t)n*227 + coff + (k-CIN)];
      }
      uint hb = f2bf_bits(f);
      uint lb = f2bf_bits(f - __uint_as_float(hb<<16));
      p[u] = (hb<<16) | lb;
    }
    *(uint4*)&slab[r*256 + (((g ^ r) & 63)<<2)] = make_uint4(p[0],p[1],p[2],p[3]);
  }
  __syncthreads();

#pragma unroll 1
  for (int l = 0; l < NL; l++){
    const int N = cfg.L[l].N, Kq = cfg.L[l].Kq, Nt = cfg.L[l].Nt;
    const int woff = cfg.L[l].woff, soff = cfg.L[l].soff, hoff = cfg.L[l].hoff;
    const int epi = cfg.L[l].epi, actf = cfg.L[l].act;
    Acc16 acc[4];
#pragma unroll
    for (int u=0;u<4;u++)
#pragma unroll
      for (int i=0;i<16;i++) acc[u].f[i] = 0.f;

#pragma unroll 1
    for (int q = 0; q < Kq; q++){
#pragma unroll
      for (int ks = 0; ks < 2; ks++){
        int g0 = (q*32 + ks*16 + hb2*8) >> 2;
        uint4 a0 = *(const uint4*)&slab[row_l*256 + ((((g0  ) ^ row_l) & 63)<<2)];
        uint4 a1 = *(const uint4*)&slab[row_l*256 + ((((g0+1) ^ row_l) & 63)<<2)];
        uint au[8] = {a0.x,a0.y,a0.z,a0.w,a1.x,a1.y,a1.z,a1.w};
        FragAB ah, al;
#pragma unroll
        for (int p=0;p<4;p++){
          ah.u[p] = (au[2*p]>>16)     | (au[2*p+1] & 0xFFFF0000u);
          al.u[p] = (au[2*p]&0xFFFFu) | (au[2*p+1]<<16);
        }
#pragma unroll
        for (int u=0;u<4;u++){
          int t = thalf + u*2;
          if (t < Nt){
            size_t fb = (size_t)woff + ((size_t)((t*Kq + q)*2 + ks))*512 + (size_t)lane*8;
            FragB bh, bl;
            bh.q = *(const uint4*)(wh + fb);
            bl.q = *(const uint4*)(wl + fb);
            acc[u].v = __builtin_amdgcn_mfma_f32_32x32x16_bf16(ah.v, bh.v, acc[u].v, 0,0,0);
            acc[u].v = __builtin_amdgcn_mfma_f32_32x32x16_bf16(al.v, bh.v, acc[u].v, 0,0,0);
            acc[u].v = __builtin_amdgcn_mfma_f32_32x32x16_bf16(ah.v, bl.v, acc[u].v, 0,0,0);
          }
        }
      }
    }
    __syncthreads();
#pragma unroll
    for (int u=0;u<4;u++){
      int t = thalf + u*2;
      if (t < Nt){
        int col = t*32 + np;
        if (col < N){
          float scv = (epi==0) ? wc[soff+col] : 0.f;
          float shv = wc[hoff+col];
#pragma unroll
          for (int reg=0;reg<16;reg++){
            int r32 = (reg&3) + 8*(reg>>2) + 4*hb2;
            float v = acc[u].f[reg];
            if (epi==0)      v = v*scv + shv;
            else             v = v + shv;
            if (actf==1)     v = v > 0.f ? v : 0.2f*v;
            if (l == NL-1){
              int gr = rb + rhalf*32 + r32;
              if (gr < M) Cout[(size_t)gr*ldc + col] = v;
            } else {
              int r = rhalf*32 + r32;
              uint hb = f2bf_bits(v);
              uint lb = f2bf_bits(v - __uint_as_float(hb<<16));
              slab[r*256 + ((((col>>2) ^ r) & 63)<<2) + (col&3)] = (hb<<16) | lb;
            }
          }
        }
      }
    }
    __syncthreads();
  }
}

// ---------------------------------------------------------------------------
// Decoder MLP with FUSED softmax-gather staging (round 12): per 64-row block,
// (A) load 20 (logit,idx) pairs/row into LDS, (B) per-row softmax (normalized
// weights in-place), (C) stage z = sum_k w_k * xf[li_k] directly. Unguarded
// 4-wide reads may stray <=28 floats past x_feat (into allocated f1b) for
// k>=227, but those slab positions multiply zero-packed weight columns.
// Compute/epilogue identical to mlp_fused<6,1>.
// ---------------------------------------------------------------------------
__global__ __launch_bounds__(256) void mlp_dec_k(
    const float* __restrict__ logits, const int* __restrict__ up_idx,
    const float* __restrict__ xf, int M,
    MCfg cfg,
    const ushort_t* __restrict__ wh, const ushort_t* __restrict__ wl,
    const float* __restrict__ wc,
    void* __restrict__ oflg, const int* __restrict__ flag)
{
  __shared__ __align__(16) uint slab[64*256];   // 65536 B
  __shared__ float lwd[64][KUP];                // 5120 B
  __shared__ int   lid[64][KUP];                // 5120 B
  const int tid = threadIdx.x;
  const int lane = tid & 63;
  const int wv = tid >> 6;
  const int np = lane & 31;
  const int hb2 = lane >> 5;
  const int rhalf = wv & 1, thalf = wv >> 1;
  const int rb = blockIdx.x * 64;
  const int row_l = rhalf*32 + np;

  // A: stage logits + indices
  for (int p = tid; p < 64*KUP; p += 256){
    int r = p / KUP, k = p % KUP;
    int gr = rb + r;
    if (gr < M){
      lwd[r][k] = logits[(size_t)gr*KUP + k];
      lid[r][k] = up_idx[(size_t)gr*KUP + k];
    } else { lwd[r][k] = 0.f; lid[r][k] = 0; }
  }
  __syncthreads();
  // B: per-row softmax (normalized weights in-place)
  if (tid < 64){
    int gr = rb + tid;
    if (gr < M){
      float mx = -1e30f;
#pragma unroll 1
      for (int k=0;k<KUP;k++) mx = fmaxf(mx, lwd[tid][k]);
      float s = 0.f;
#pragma unroll 1
      for (int k=0;k<KUP;k++){ float w = expf(lwd[tid][k]-mx); lwd[tid][k] = w; s += w; }
      float inv = 1.f/s;
#pragma unroll 1
      for (int k=0;k<KUP;k++) lwd[tid][k] *= inv;
    } else {
#pragma unroll 1
      for (int k=0;k<KUP;k++) lwd[tid][k] = 0.f;
    }
  }
  __syncthreads();
  // C: gather-weighted staging
  for (int e = tid; e < 64*64; e += 256){
    int r = e >> 6, g = e & 63;
    int cb = g*4;
    float f0=0.f, f1=0.f, f2=0.f, f3=0.f;
#pragma unroll 1
    for (int k=0;k<KUP;k++){
      float w = lwd[r][k];
      const float* src = xf + (size_t)lid[r][k]*227 + cb;
      f0 += w*src[0]; f1 += w*src[1]; f2 += w*src[2]; f3 += w*src[3];
    }
    float fv[4] = {f0,f1,f2,f3};
    uint p[4];
#pragma unroll
    for (int u=0;u<4;u++){
      uint hb = f2bf_bits(fv[u]);
      uint lb = f2bf_bits(fv[u] - __uint_as_float(hb<<16));
      p[u] = (hb<<16) | lb;
    }
    *(uint4*)&slab[r*256 + (((g ^ r) & 63)<<2)] = make_uint4(p[0],p[1],p[2],p[3]);
  }
  __syncthreads();

#pragma unroll 1
  for (int l = 0; l < 6; l++){
    const int N = cfg.L[l].N, Kq = cfg.L[l].Kq, Nt = cfg.L[l].Nt;
    const int woff = cfg.L[l].woff, hoff = cfg.L[l].hoff;
    const int epi = cfg.L[l].epi, actf = cfg.L[l].act;
    const float gmul = cfg.L[l].gmul;
    Acc16 acc[4];
#pragma unroll
    for (int u=0;u<4;u++)
#pragma unroll
      for (int i=0;i<16;i++) acc[u].f[i] = 0.f;

#pragma unroll 1
    for (int q = 0; q < Kq; q++){
#pragma unroll
      for (int ks = 0; ks < 2; ks++){
        int g0 = (q*32 + ks*16 + hb2*8) >> 2;
        uint4 a0 = *(const uint4*)&slab[row_l*256 + ((((g0  ) ^ row_l) & 63)<<2)];
        uint4 a1 = *(const uint4*)&slab[row_l*256 + ((((g0+1) ^ row_l) & 63)<<2)];
        uint au[8] = {a0.x,a0.y,a0.z,a0.w,a1.x,a1.y,a1.z,a1.w};
        FragAB ah, al;
#pragma unroll
        for (int p=0;p<4;p++){
          ah.u[p] = (au[2*p]>>16)     | (au[2*p+1] & 0xFFFF0000u);
          al.u[p] = (au[2*p]&0xFFFFu) | (au[2*p+1]<<16);
        }
#pragma unroll
        for (int u=0;u<4;u++){
          int t = thalf + u*2;
          if (t < Nt){
            size_t fb = (size_t)woff + ((size_t)((t*Kq + q)*2 + ks))*512 + (size_t)lane*8;
            FragB bh, bl;
            bh.q = *(const uint4*)(wh + fb);
            bl.q = *(const uint4*)(wl + fb);
            acc[u].v = __builtin_amdgcn_mfma_f32_32x32x16_bf16(ah.v, bh.v, acc[u].v, 0,0,0);
            acc[u].v = __builtin_amdgcn_mfma_f32_32x32x16_bf16(al.v, bh.v, acc[u].v, 0,0,0);
            acc[u].v = __builtin_amdgcn_mfma_f32_32x32x16_bf16(ah.v, bl.v, acc[u].v, 0,0,0);
          }
        }
      }
    }
    __syncthreads();
#pragma unroll
    for (int u=0;u<4;u++){
      int t = thalf + u*2;
      if (t < Nt){
        int col = t*32 + np;
        if (col < N){
          float shv = wc[hoff+col];
#pragma unroll
          for (int reg=0;reg<16;reg++){
            int r32 = (reg&3) + 8*(reg>>2) + 4*hb2;
            float v = acc[u].f[reg];
            if (epi==1) v = v + shv;
            else        v = (v + shv)*gmul;
            if (actf==2) v = __sinf(v);
            if (l == 5){
              int gr = rb + rhalf*32 + r32;
              if (gr < M){
                if (!(fabsf(v) < 1e30f)) v = 777.0f;  // canary
                size_t oi = (size_t)gr*3 + col;
                if (flag[0]) ((bf16*)oflg)[oi] = __float2bfloat16(v);
                else         ((float*)oflg)[oi] = v;
              }
            } else {
              int r = rhalf*32 + r32;
              uint hb = f2bf_bits(v);
              uint lb = f2bf_bits(v - __uint_as_float(hb<<16));
              slab[r*256 + ((((col>>2) ^ r) & 63)<<2) + (col&3)] = (hb<<16) | lb;
            }
          }
        }
      }
    }
    __syncthreads();
  }
}

// ---------------------------------------------------------------------------
// MFMA KNN (validated round 7).
// ---------------------------------------------------------------------------
#define INS5(tv, tj, v, j) \
  if ((v) > tv[4]){ tv[4]=(v); tj[4]=(j); \
    _Pragma("unroll") \
    for (int q=4;q>0;q--) \
      if (tv[q] > tv[q-1]){ float tf=tv[q-1]; tv[q-1]=tv[q]; tv[q]=tf; \
                            int ti=tj[q-1]; tj[q-1]=tj[q]; tj[q]=ti; } }

__global__ __launch_bounds__(256) void knn_mfma_k(
    const ushort_t* __restrict__ ahi, const ushort_t* __restrict__ alo,
    const ushort_t* __restrict__ bhi, const ushort_t* __restrict__ blo,
    int* __restrict__ out)
{
  __shared__ float mv[4][32][5];
  __shared__ int   mjj[4][32][5];
  const int tid = threadIdx.x;
  const int lane = tid & 63;
  const int wv = tid >> 6;
  const int np = lane & 31;
  const int hb2 = lane >> 5;
  const int it = blockIdx.x;
  const int ig = it*32 + np;

  FragB vh[5], vl[5];
  {
    size_t bb = (size_t)(it*5)*512 + (size_t)lane*8;
#pragma unroll
    for (int kc=0;kc<5;kc++){
      vh[kc].q = *(const uint4*)(bhi + bb + kc*512);
      vl[kc].q = *(const uint4*)(blo + bb + kc*512);
    }
  }

  float tv[5] = {-1e30f,-1e30f,-1e30f,-1e30f,-1e30f};
  int   tj[5] = {0,0,0,0,0};

  FragB uh[5], ul[5], nh[5], nl[5];
  {
    size_t ab = (size_t)(wv*5)*512 + (size_t)lane*8;
#pragma unroll
    for (int kc=0;kc<5;kc++){
      uh[kc].q = *(const uint4*)(ahi + ab + kc*512);
      ul[kc].q = *(const uint4*)(alo + ab + kc*512);
    }
  }

#pragma unroll 1
  for (int t = 0; t < NTILE/4; t++){
    int jt = wv + t*4;
    if (t+1 < NTILE/4){
      size_t an = (size_t)((jt+4)*5)*512 + (size_t)lane*8;
#pragma unroll
      for (int kc=0;kc<5;kc++){
        nh[kc].q = *(const uint4*)(ahi + an + kc*512);
        nl[kc].q = *(const uint4*)(alo + an + kc*512);
      }
    }
    Acc16 acc;
#pragma unroll
    for (int q=0;q<16;q++) acc.f[q] = 0.f;
#pragma unroll
    for (int kc=0;kc<5;kc++){
      acc.v = __builtin_amdgcn_mfma_f32_32x32x16_bf16(uh[kc].v, vh[kc].v, acc.v, 0,0,0);
      acc.v = __builtin_amdgcn_mfma_f32_32x32x16_bf16(ul[kc].v, vh[kc].v, acc.v, 0,0,0);
      acc.v = __builtin_amdgcn_mfma_f32_32x32x16_bf16(uh[kc].v, vl[kc].v, acc.v, 0,0,0);
    }
    int jb = jt*32 + 4*hb2;
#pragma unroll
    for (int reg=0;reg<16;reg++){
      int j = jb + (reg&3) + 8*(reg>>2);
      float v = acc.f[reg];
      if (j != ig) { INS5(tv, tj, v, j); }
    }
    if (t+1 < NTILE/4){
#pragma unroll
      for (int kc=0;kc<5;kc++){ uh[kc] = nh[kc]; ul[kc] = nl[kc]; }
    }
  }

#pragma unroll
  for (int s=0;s<5;s++){
    float ov = __shfl_xor(tv[s], 32, 64);
    int   oj = __shfl_xor(tj[s], 32, 64);
    INS5(tv, tj, ov, oj);
  }
  if (hb2 == 0){
#pragma unroll
    for (int s=0;s<5;s++){ mv[wv][np][s] = tv[s]; mjj[wv][np][s] = tj[s]; }
  }
  __syncthreads();
  if (tid < 32){
    float bv[5]; int bj[5];
#pragma unroll
    for (int s=0;s<5;s++){ bv[s] = mv[0][tid][s]; bj[s] = mjj[0][tid][s]; }
#pragma unroll
    for (int w=1;w<4;w++)
#pragma unroll
      for (int s=0;s<5;s++){
        float v = mv[w][tid][s]; int j = mjj[w][tid][s];
        INS5(bv, bj, v, j);
      }
    int gi = it*32 + tid;
#pragma unroll
    for (int s=0;s<5;s++) out[gi*KNN_K + s] = bj[s];
  }
}

// ---------------------------------------------------------------------------
// Fused 8-layer SIREN + head (v9, validated round 11): register-resident acts
// + sigma-fold + 1/2pi-folded weights -> raw v_sin. One barrier.
// ---------------------------------------------------------------------------
__global__ __launch_bounds__(256) void siren_fused_k(
    const void* __restrict__ upin,
    const ushort_t* __restrict__ wf16,
    const float* __restrict__ W0c, const float* __restrict__ S0c, const float* __restrict__ H0c,
    const float* __restrict__ HRc,
    const float* __restrict__ WFc, const float* __restrict__ BFc,
    float* __restrict__ logits, const int* __restrict__ flag)
{
  __shared__ float intile[4*32*8];                   // 4096 B
  __shared__ __align__(16) float w0s[128*8];         // 4096 B (scale*inv2pi, bias slot 7)
  __shared__ __align__(16) float hrs[7*128];         // 3584 B biases * inv2pi
  __shared__ __align__(16) float wfs[128];
  __shared__ float bfs[1];

  const int tid  = threadIdx.x;
  const int lane = tid & 63;
  const int wv   = tid >> 6;
  const int np   = lane & 31;
  const int hb2  = lane >> 5;
  const int rowbase = blockIdx.x * 128 + wv * 32;
  const int isbf = flag[0];
  float* intw = intile + wv*32*8;

  for (int e = tid; e < 128*7; e += 256){
    int c = e/7, k = e%7;
    w0s[c*8+k] = W0c[e]*S0c[c]*INV2PI;
  }
  if (tid < 128) w0s[tid*8+7] = H0c[tid]*INV2PI;
  for (int e = tid; e < 7*128; e += 256) hrs[e] = HRc[e]*INV2PI;
  if (tid < 128) wfs[tid] = WFc[tid];
  if (tid == 0) bfs[0] = BFc[0];
  for (int e = lane; e < 32*7; e += 64) {
    int r = e/7, k = e%7;
    int gr = rowbase + r;
    float v = 0.f;
    if (gr < UP_ROWS)
      v = isbf ? b2f(((const bf16*)upin)[(size_t)gr*7+k]) : ((const float*)upin)[(size_t)gr*7+k];
    intw[r*8+k] = v;
  }
  __syncthreads();   // staged tables ready; ONLY barrier in the kernel

  uint st0[16], st1[16];   // per group: [j0,j1] and [j2,j3] packed fp16
  {
    float xin[7];
#pragma unroll
    for (int k=0;k<7;k++) xin[k] = intw[np*8+k];
#pragma unroll
    for (int g = 0; g < 16; g++){
      float xs[4];
#pragma unroll
      for (int j = 0; j < 4; j++){
        int c = g*8 + hb2*4 + j;
        const float4 wa = *(const float4*)&w0s[c*8];
        const float4 wb = *(const float4*)&w0s[c*8+4];
        float a = wb.w;                     // bias (pre-scaled)
        a += xin[0]*wa.x; a += xin[1]*wa.y; a += xin[2]*wa.z; a += xin[3]*wa.w;
        a += xin[4]*wb.x; a += xin[5]*wb.y; a += xin[6]*wb.z;
        xs[j] = sinrev(a);
      }
      H2U u0,u1;
      u0.h = __builtin_amdgcn_cvt_pkrtz(xs[0],xs[1]);
      u1.h = __builtin_amdgcn_cvt_pkrtz(xs[2],xs[3]);
      st0[g] = u0.u; st1[g] = u1.u;
    }
  }

  FragH fr[8];
#pragma unroll
  for (int m = 0; m < 8; m++)
    fr[m].q = make_uint4(st0[2*m], st1[2*m], st0[2*m+1], st1[2*m+1]);

  uint nst0[16], nst1[16];
#pragma unroll 1
  for (int l = 0; l < 7; l++) {
#pragma unroll
    for (int tp = 0; tp < 2; tp++){
      Acc16 acc0, acc1;
#pragma unroll
      for (int i=0;i<16;i++){ acc0.f[i] = 0.f; acc1.f[i] = 0.f; }
#pragma unroll
      for (int m = 0; m < 8; m++){
        int fb = (((l*8 + m)*4 + tp*2) << 9) + lane*8;
        FragH bh0, bh1;
        bh0.q = *(const uint4*)(wf16 + fb);
        bh1.q = *(const uint4*)(wf16 + fb + 512);
        acc0.v = __builtin_amdgcn_mfma_f32_32x32x16_f16(bh0.v, fr[m].v, acc0.v, 0,0,0);
        acc1.v = __builtin_amdgcn_mfma_f32_32x32x16_f16(bh1.v, fr[m].v, acc1.v, 0,0,0);
      }
#pragma unroll
      for (int rg = 0; rg < 4; rg++){
        int g0 = (tp*2+0)*4 + rg;
        const float4 b0v = *(const float4*)&hrs[l*128 + g0*8 + hb2*4];
        float x0 = sinrev(acc0.f[rg*4+0] + b0v.x);
        float x1 = sinrev(acc0.f[rg*4+1] + b0v.y);
        float x2 = sinrev(acc0.f[rg*4+2] + b0v.z);
        float x3 = sinrev(acc0.f[rg*4+3] + b0v.w);
        H2U u0,u1;
        u0.h = __builtin_amdgcn_cvt_pkrtz(x0,x1);
        u1.h = __builtin_amdgcn_cvt_pkrtz(x2,x3);
        nst0[g0] = u0.u; nst1[g0] = u1.u;

        int g1 = (tp*2+1)*4 + rg;
        const float4 b1v = *(const float4*)&hrs[l*128 + g1*8 + hb2*4];
        float y0 = sinrev(acc1.f[rg*4+0] + b1v.x);
        float y1 = sinrev(acc1.f[rg*4+1] + b1v.y);
        float y2 = sinrev(acc1.f[rg*4+2] + b1v.z);
        float y3 = sinrev(acc1.f[rg*4+3] + b1v.w);
        H2U v0,v1;
        v0.h = __builtin_amdgcn_cvt_pkrtz(y0,y1);
        v1.h = __builtin_amdgcn_cvt_pkrtz(y2,y3);
        nst0[g1] = v0.u; nst1[g1] = v1.u;
      }
    }
    if (l < 6){
#pragma unroll
      for (int m = 0; m < 8; m++)
        fr[m].q = make_uint4(nst0[2*m], nst1[2*m], nst0[2*m+1], nst1[2*m+1]);
    }
  }

  {
    float a = 0.f;
#pragma unroll
    for (int g = 0; g < 16; g++){
      const float4 w4 = *(const float4*)&wfs[g*8 + hb2*4];
      H2U u0,u1; u0.u = nst0[g]; u1.u = nst1[g];
      a += (float)u0.h.x*w4.x + (float)u0.h.y*w4.y
         + (float)u1.h.x*w4.z + (float)u1.h.y*w4.w;
    }
    a += __shfl_xor(a, 32, 64);
    int gr = rowbase + np;
    if (hb2 == 0 && gr < UP_ROWS) logits[gr] = a + bfs[0];
  }
}

// ---------------------------------------------------------------------------
__global__ void featin_k(const void* __restrict__ ldx, const void* __restrict__ pos,
                         float* __restrict__ xf, const int* __restrict__ flag){
  int i = blockIdx.x*256 + threadIdx.x;
  if (i >= N_PTS*35) return;
  int n = i / 35, c = i % 35;
  float v;
  if (flag[0]) {
    v = (c < 3) ? b2f(((const bf16*)ldx)[n*3+c]) : b2f(((const bf16*)pos)[n*32 + (c-3)]);
  } else {
    v = (c < 3) ? ((const float*)ldx)[n*3+c] : ((const float*)pos)[n*32 + (c-3)];
  }
  xf[(size_t)n*227 + c] = v;
}

// kmax with separate element stride (ld)
__global__ void kmax_k(const float* __restrict__ e2, int C, int ld, float* __restrict__ f1,
                       int n0, int np){
  int i = blockIdx.x*256 + threadIdx.x;
  if (i >= np*C) return;
  int nl = i / C, c = i % C;
  float v = -1e30f;
  for (int k=0;k<KNN_K;k++) v = fmaxf(v, e2[((size_t)nl*KNN_K+k)*ld + c]);
  f1[(size_t)(n0+nl)*C + c] = v;
}

template<int C>
__global__ __launch_bounds__(256) void reduce1_k(const float* __restrict__ X, int n,
                                                 float* __restrict__ pmax, float* __restrict__ psum){
  const int tid = threadIdx.x;
  const int c = tid % C;
  const int r0 = tid / C;
  const int TPR = 256 / C;
  float vmax = -1e30f, vsum = 0.f;
  for (int row = blockIdx.x * TPR + r0; row < n; row += gridDim.x * TPR) {
    float v = X[(size_t)row * C + c];
    vmax = fmaxf(vmax, v); vsum += v;
  }
  __shared__ float smax[256], ssum[256];
  smax[tid]=vmax; ssum[tid]=vsum;
  __syncthreads();
  if (tid < C) {
    for (int q=1;q<TPR;q++){ vmax=fmaxf(vmax, smax[q*C+c]); vsum += ssum[q*C+c]; }
    pmax[blockIdx.x*C + c] = vmax; psum[blockIdx.x*C + c] = vsum;
  }
}

// merged reduce2 + foldshift
template<int C>
__global__ __launch_bounds__(256) void red2fold_k(
    const float* __restrict__ pmax, const float* __restrict__ psum,
    int nblk, float invn,
    const float* __restrict__ W, int ldw, int off1, int off2,
    const float* __restrict__ scale, const float* __restrict__ shift,
    float* __restrict__ out, int N)
{
  __shared__ float smax[C], ssum[C];
  int tid = threadIdx.x;
  if (tid < C){
    float vmax=-1e30f, vsum=0.f;
    for (int b=0;b<nblk;b++){ vmax=fmaxf(vmax,pmax[b*C+tid]); vsum+=psum[b*C+tid]; }
    smax[tid]=vmax; ssum[tid]=vsum*invn;
  }
  __syncthreads();
  for (int n = tid; n < N; n += 256){
    const float* wr = W + (size_t)n*ldw;
    float s = 0.f;
    for (int j=0;j<C;j++) s += wr[off1+j]*smax[j];
    for (int j=0;j<C;j++) s += wr[off2+j]*ssum[j];
    out[n] = s*scale[n] + shift[n];
  }
}

// varying-channels-only concat (fmax/favg folded into shift vectors)
__global__ void concat2_k(const float* __restrict__ xf, int coff, int CF,
                          const float* __restrict__ f1, int C,
                          float* __restrict__ h, int n0, int np){
  int W = CF + C;
  int i = blockIdx.x*256 + threadIdx.x;
  if (i >= np*W) return;
  int nl = i / W, c = i % W;
  int n = n0 + nl;
  float v = (c < CF) ? xf[(size_t)n*227 + coff + c] : f1[(size_t)n*C + (c-CF)];
  h[(size_t)nl*W + c] = v;
}

__global__ void norms_k(const float* __restrict__ xf, float* __restrict__ nr){
  int n = blockIdx.x*256 + threadIdx.x;
  if (n >= N_PTS) return;
  const float* p = xf + (size_t)n*227 + 35;
  float s = 0.f;
  for (int d=0;d<64;d++) s += p[d]*p[d];
  nr[n] = s;
}

// ---------------------------------------------------------------------------
extern "C" void kernel_launch(void* const* d_in, const int* in_sizes, int n_in,
                              void* d_out, int out_size, void* d_ws, size_t ws_size,
                              hipStream_t stream) {
  const int *idx0  = (const int*)d_in[3];
  const int *upidx = (const int*)d_in[37];

  // ---- workspace layout (floats) ----
  float* ws = (float*)d_ws;
  float* x_feat = ws;                     // [N,227]
  float* f1b    = ws + 3602944;           // [N,128]
  float* pmax   = ws + 5634560;           // [256*128]
  float* psum   = ws + 5667328;           // [256*128]
  float* fold0  = pmax + 24576;           // [192]
  float* fold1  = psum + 24576;           // [384]
  int*   flag   = (int*)(ws + 5700352);
  int*   idx1   = (int*)(ws + 5700368);   // N*5
  float* nrm    = ws + 5779728;           // N
  float* logits = ws + 5795600;           // UP_ROWS
  float* wcvt   = ws + 6508352;           // 706,020 fp32 weights
  float* S      = ws + 7214400;           // scratch arena (9,662,464 floats)
  ushort_t* whi  = (ushort_t*)(S + 9662464);  // siren fp16 plane (114688)
  ushort_t* wlo  = whi + 114688;
  ushort_t* gwhi = wlo + 114688;              // mlp planes (503808 each)
  ushort_t* gwlo = gwhi + 503808;

  const size_t NEED = (size_t)(7214400 + 9662464) * 4
                    + (size_t)(114688*2 + 503808*2) * 2;   // ~70.0 MB
  if (ws_size < NEED) {
    fillmark_k<<<CDIV(out_size,256),256,0,stream>>>((bf16*)d_out, out_size);
    return;
  }

  // ---- dtype flag + one-shot weight conversion to fp32 ----
  flag_k<<<1,64,0,stream>>>((const uint*)d_in[2], flag);
  CvtTab tab;
  int wcoff = 0, seg = 0;
  auto CVT = [&](int i, int n)->const float* {
    tab.src[seg] = d_in[i]; tab.start[seg] = wcoff; seg++;
    const float* p = wcvt + wcoff; wcoff += n;
    return p;
  };
  const float *E0W1=CVT(4,8960),  *E0S1=CVT(5,128),  *E0H1=CVT(6,128),
              *E0W2=CVT(7,8192),  *E0B2=CVT(8,64);
  const float *F0W1=CVT(9,43584), *F0S1=CVT(10,192), *F0H1=CVT(11,192),
              *F0W2=CVT(12,24576),*F0S2=CVT(13,128), *F0H2=CVT(14,128),
              *F0W3=CVT(15,8192), *F0S3=CVT(16,64),  *F0H3=CVT(17,64),
              *F0W4=CVT(18,4096), *F0B4=CVT(19,64);
  const float *E1W1=CVT(20,32768),*E1S1=CVT(21,256), *E1H1=CVT(22,256),
              *E1W2=CVT(23,32768),*E1B2=CVT(24,128);
  const float *F1W1=CVT(25,172032),*F1S1=CVT(26,384),*F1H1=CVT(27,384),
              *F1W2=CVT(28,98304),*F1S2=CVT(29,256), *F1H2=CVT(30,256),
              *F1W3=CVT(31,32768),*F1S3=CVT(32,128), *F1H3=CVT(33,128),
              *F1W4=CVT(34,16384),*F1B4=CVT(35,128);
  const float *UPW0=CVT(38,896),  *UPS0=CVT(39,128), *UPH0=CVT(40,128),
              *UPWR=CVT(41,114688),*UPSR=CVT(42,896),*UPHR=CVT(43,896),
              *UPWF=CVT(44,128),  *UPBF=CVT(45,1);
  const float *DW0=CVT(46,58112), *DB0=CVT(47,256),
              *DW1=CVT(48,32768), *DB1=CVT(49,128),
              *DW2=CVT(50,8192),  *DB2=CVT(51,64),
              *DW3=CVT(52,2048),  *DB3=CVT(53,32),
              *DW4=CVT(54,512),   *DB4=CVT(55,16),
              *DWF=CVT(56,48),    *DBF=CVT(57,3);
  cvt_all_k<<<CDIV(wcoff,256),256,0,stream>>>(tab, wcvt, flag, wcoff);

  // siren fp16 plane (scale + 1/2pi + sigma folded)
  packfrag16_k<<<CDIV(114688,256),256,0,stream>>>(UPWR, UPSR, whi, 114688);

  // mlp planes in ONE batched launch
  PackTab ptab;
  int offs[18];
  int ptotal = 0;
  {
    int q = 0;
    auto REG = [&](const float* s, int N, int K, int ldk, int Kpad){
      ptab.src[q]=s; ptab.N[q]=N; ptab.K[q]=K; ptab.ldk[q]=ldk; ptab.Kpad[q]=Kpad;
      ptab.start[q]=ptotal; offs[q]=ptotal;
      ptotal += CDIV(N,32)*32*Kpad; q++;
    };
    REG(F0W1,192, 99,227,128);                         // const-folded K
    REG(F0W2,128,192,192,192); REG(F0W3,64,128,128,128); REG(F0W4,64,64,64,64);
    REG(DW0,256,227,227,256);  REG(DW1,128,256,256,256);  REG(DW2,64,128,128,128);
    REG(DW3,32,64,64,64);      REG(DW4,16,32,32,32);      REG(DWF,3,16,16,32);
    REG(E0W1,128,70,70,96);    REG(E0W2,64,128,128,128);
    REG(E1W1,256,128,128,128); REG(E1W2,128,256,256,256);
    REG(F1W3,128,256,256,256); REG(F1W4,128,128,128,128);
    REG(F1W1,384,192,448,192);   // offs[16]: fc1 gemm1 (folded K=192)
    REG(F1W2,256,384,384,384);   // offs[17]: fc1 gemm2
  }
  packw_all_k<<<CDIV(ptotal,256),256,0,stream>>>(ptab, gwhi, gwlo, ptotal);

  auto OFF = [&](const float* p){ return (int)(p - wcvt); };
  const int HOFF0 = (int)(fold0 - wcvt);
  MCfg cfc0{};
  cfc0.L[0] = { 99,192,4,6, offs[0], OFF(F0S1), HOFF0,     0,1, 0.f};
  cfc0.L[1] = {192,128,6,4, offs[1], OFF(F0S2), OFF(F0H2), 0,1, 0.f};
  cfc0.L[2] = {128, 64,4,2, offs[2], OFF(F0S3), OFF(F0H3), 0,1, 0.f};
  cfc0.L[3] = { 64, 64,2,2, offs[3], 0,         OFF(F0B4), 1,0, 0.f};
  MCfg cdec{};
  cdec.L[0] = {227,256,8,8, offs[4], 0, OFF(DB0), 2,2, 30.f};
  cdec.L[1] = {256,128,8,4, offs[5], 0, OFF(DB1), 1,2, 0.f};
  cdec.L[2] = {128, 64,4,2, offs[6], 0, OFF(DB2), 1,2, 0.f};
  cdec.L[3] = { 64, 32,2,1, offs[7], 0, OFF(DB3), 1,2, 0.f};
  cdec.L[4] = { 32, 16,1,1, offs[8], 0, OFF(DB4), 1,2, 0.f};
  cdec.L[5] = { 16,  3,1,1, offs[9], 0, OFF(DBF), 1,0, 0.f};
  MCfg ce0{};
  ce0.L[0] = { 70,128,3,4, offs[10], OFF(E0S1), OFF(E0H1), 0,1, 0.f};
  ce0.L[1] = {128, 64,4,2, offs[11], 0,         OFF(E0B2), 1,0, 0.f};
  MCfg ce1{};
  ce1.L[0] = {128,256,4,8, offs[12], OFF(E1S1), OFF(E1H1), 0,1, 0.f};
  ce1.L[1] = {256,128,8,4, offs[13], 0,         OFF(E1B2), 1,0, 0.f};
  MCfg cf1t{};
  cf1t.L[0] = {256,128,8,4, offs[14], OFF(F1S3), OFF(F1H3), 0,1, 0.f};
  cf1t.L[1] = {128,128,4,4, offs[15], 0,         OFF(F1B4), 1,0, 0.f};

  const float invN = 1.f/(float)N_PTS;

  featin_k<<<CDIV(N_PTS*35,256),256,0,stream>>>(d_in[1], d_in[2], x_feat, flag);

  // ---- phase 1: emb block 0 — fused gather+MLP (no edge buffer)
  {
    float* eOut = S;               // [79360,64] = 5,079,040
    mlp_edge_k<2><<<CDIV(N_EDGE,64),256,0,stream>>>(
        x_feat, 0, 35, idx0, 0, N_EDGE, ce0, gwhi,gwlo,wcvt, eOut,64);
    kmax_k<<<CDIV(N_PTS*64,256),256,0,stream>>>(eOut, 64, 64, f1b, 0, N_PTS);
  }
  reduce1_k<64><<<256,256,0,stream>>>(f1b, N_PTS, pmax, psum);
  red2fold_k<64><<<1,256,0,stream>>>(pmax, psum, 256, invN,
                                     F0W1,227, 99,163, F0S1,F0H1, fold0, 192);
  // fc0: varying-only concat (99 ch) then ONE fused MLP
  {
    float* h = S;   // [N,99]
    concat2_k<<<CDIV(N_PTS*99,256),256,0,stream>>>(x_feat,0,35, f1b,64, h, 0, N_PTS);
    mlp_fused_k<4,0><<<CDIV(N_PTS,64),256,0,stream>>>(
        h,99,99,N_PTS, cfc0, gwhi,gwlo,wcvt, x_feat+35,227, nullptr, flag);
  }

  // ---- phase 2: dynamic KNN (MFMA)
  norms_k<<<CDIV(N_PTS,256),256,0,stream>>>(x_feat, nrm);
  {
    const int PLANE = NTILE*5*64*8;
    ushort_t* ajhi = (ushort_t*)S;
    ushort_t* ajlo = ajhi + PLANE;
    ushort_t* bihi = ajlo + PLANE;
    ushort_t* bilo = bihi + PLANE;
    packknn_k<<<CDIV(PLANE,256),256,0,stream>>>(x_feat, nrm, ajhi, ajlo, bihi, bilo);
    knn_mfma_k<<<NTILE,256,0,stream>>>(ajhi, ajlo, bihi, bilo, idx1);
  }

  // ---- phase 3: emb block 1 — fused gather+MLP, 2 chunks
  {
    const int P1 = 7936;             // points/chunk -> 39680 edges
    for (int n0 = 0; n0 < N_PTS; n0 += P1) {
      int np = N_PTS - n0; if (np > P1) np = P1;
      int ne = np * KNN_K;
      float* eOut = S;               // [39680,128] = 5,079,040
      mlp_edge_k<2><<<CDIV(ne,64),256,0,stream>>>(
          x_feat, 35, 64, idx1, n0, ne, ce1, gwhi,gwlo,wcvt, eOut,128);
      kmax_k<<<CDIV(np*128,256),256,0,stream>>>(eOut, 128, 128, f1b, n0, np);
    }
  }
  reduce1_k<128><<<256,256,0,stream>>>(f1b, N_PTS, pmax, psum);
  red2fold_k<128><<<1,256,0,stream>>>(pmax, psum, 256, invN,
                                      F1W1,448, 192,320, F1S1,F1H1, fold1, 384);
  // ---- fc1: full-N (no chunking)
  {
    float* h  = S;                   // [N,192]
    float* a1 = S + 3047424;         // [N,384]
    int gx = CDIV(N_PTS,64);         // 248
    concat2_k<<<CDIV(N_PTS*192,256),256,0,stream>>>(x_feat,35,64, f1b,128, h, 0, N_PTS);
    gemm_mfma_k<1><<<dim3(gx,3),256,0,stream>>>(h,192,192,N_PTS, gwhi,gwlo, offs[16],6,
                                                F1S1,fold1, a1,384, 384);
    gemm_mfma_k<1><<<dim3(gx,2),256,0,stream>>>(a1,384,384,N_PTS, gwhi,gwlo, offs[17],12,
                                                F1S2,F1H2, h,256, 256);
    mlp_fused_k<2,0><<<gx,256,0,stream>>>(
        h,256,256,N_PTS, cf1t, gwhi,gwlo,wcvt, x_feat+99,227, nullptr, flag);
  }

  // ---- phase 4: fused SIREN -> logits
  siren_fused_k<<<CDIV(UP_ROWS,128),256,0,stream>>>(
      d_in[36], whi, UPW0, UPS0, UPH0, UPHR, UPWF, UPBF, logits, flag);

  // ---- phase 5: decoder with FUSED softmax-gather staging (no zbuf)
  mlp_dec_k<<<CDIV(M_PTS,64),256,0,stream>>>(
      logits, upidx, x_feat, M_PTS, cdec, gwhi,gwlo,wcvt, d_out, flag);
}

// Round 13
// 1778.619 us; speedup vs baseline: 1.1237x; 1.1237x over previous
//
#include <hip/hip_runtime.h>
#include <hip/hip_bf16.h>
#include <math.h>

#define N_PTS 15872
#define M_PTS 35637
#define KNN_K 5
#define KUP   20
#define UP_ROWS (M_PTS * KUP)   // 712740
#define NTILE (N_PTS/32)        // 496 i/j tiles
#define N_EDGE (N_PTS*KNN_K)    // 79360
#define CDIV(a,b) (((a)+(b)-1)/(b))
#define INV2PI 0.15915494309189535f

typedef __hip_bfloat16 bf16;
typedef unsigned int uint;
typedef unsigned short ushort_t;
__device__ __forceinline__ float b2f(bf16 x){ return __bfloat162float(x); }

// round-to-nearest-even fp32 -> bf16 bit pattern (finite inputs)
__device__ __forceinline__ uint f2bf_bits(float x){
  uint u = __float_as_uint(x);
  return (u + 0x7FFFu + ((u>>16)&1u)) >> 16;
}

// fp32 -> fp16 bits (RNE via hardware cvt)
__device__ __forceinline__ ushort_t f2h_bits(float x){
  union { _Float16 h; ushort_t u; } c; c.h = (_Float16)x; return c.u;
}

// sin with input in REVOLUTIONS (v_sin_f32 semantics); weights/biases are
// pre-scaled by 1/2pi so this is a single VALU op.
__device__ __forceinline__ float sinrev(float x){
#if __has_builtin(__builtin_amdgcn_sinf)
  return __builtin_amdgcn_sinf(x);
#else
  return __sinf(x * 6.283185307179586f);
#endif
}

typedef __attribute__((ext_vector_type(8))) short bf16x8;
typedef __attribute__((ext_vector_type(8))) _Float16 f16x8;
typedef __attribute__((ext_vector_type(2))) __fp16 fp16x2_t;
typedef __attribute__((ext_vector_type(16))) float f32x16;
union FragAB { bf16x8 v; uint u[4]; };
union FragB  { bf16x8 v; uint4 q; };
union FragH  { f16x8 v; uint4 q; _Float16 h[8]; };
union Acc16  { f32x16 v; float f[16]; };
union H2U    { fp16x2_t h; uint u; };

// ---------------------------------------------------------------------------
__global__ void flag_k(const uint* __restrict__ pos_raw, int* __restrict__ flag){
  if (threadIdx.x == 0 && blockIdx.x == 0)
    flag[0] = (pos_raw[0] == 0x3F800000u) ? 1 : 0;
}

struct CvtTab { const void* src[52]; int start[52]; };
__global__ __launch_bounds__(256) void cvt_all_k(CvtTab tab, float* __restrict__ dst,
                                                 const int* __restrict__ flag, int total){
  int i = blockIdx.x*256 + threadIdx.x;
  if (i >= total) return;
  int s = 0;
#pragma unroll 1
  for (int k = 1; k < 52; k++) if (tab.start[k] <= i) s = k;
  int off = i - tab.start[s];
  float v = flag[0] ? b2f(((const bf16*)tab.src[s])[off]) : ((const float*)tab.src[s])[off];
  dst[i] = v;
}

// pack SIREN 128x128 weights into frag-major fp16 plane; per-layer output
// scale AND 1/2pi folded in (epilogue uses raw v_sin on revolutions).
// sigma-fold: store W[n][sigma(k)] at physical slot k so the consuming
// lane's next-layer B-frag assembles from its OWN registers.
__global__ void packfrag16_k(const float* __restrict__ w, const float* __restrict__ sr,
                             ushort_t* __restrict__ out, int n){
  int i = blockIdx.x*256 + threadIdx.x;
  if (i >= n) return;
  int j = i & 7;
  int lam = (i >> 3) & 63;
  int fg = i >> 9;
  int t = fg & 3, ks = (fg >> 2) & 1, Q = (fg >> 3) & 3, l = fg >> 5;
  int nn = t*32 + (lam & 31);
  int kk = Q*32 + ks*16 + ((j>>2)<<3) + ((lam>>5)<<2) + (j&3);   // sigma-fold
  float x = w[l*16384 + nn*128 + kk] * sr[l*128 + nn] * INV2PI;
  out[i] = f2h_bits(x);
}

// batched frag-major split-bf16 pack for all 18 weight matrices in ONE launch.
struct PackTab { const float* src[18]; int N[18], K[18], ldk[18], Kpad[18], start[18]; };
__global__ __launch_bounds__(256) void packw_all_k(PackTab t, ushort_t* __restrict__ whi,
                                                   ushort_t* __restrict__ wlo, int total){
  int i = blockIdx.x*256 + threadIdx.x;
  if (i >= total) return;
  int s = 0;
#pragma unroll 1
  for (int q = 1; q < 18; q++) if (t.start[q] <= i) s = q;
  int ii = i - t.start[s];
  int j = ii & 7;
  int lane = (ii >> 3) & 63;
  int fr = ii >> 9;
  int nq = t.Kpad[s] >> 5;
  int ks = fr & 1;
  int q  = (fr >> 1) % nq;
  int nt = (fr >> 1) / nq;
  int n = nt*32 + (lane & 31);
  int k = q*32 + ks*16 + (lane >> 5)*8 + j;
  float x = (n < t.N[s] && k < t.K[s]) ? t.src[s][(size_t)n*t.ldk[s] + k] : 0.f;
  uint hb = f2bf_bits(x);
  uint lb = f2bf_bits(x - __uint_as_float(hb << 16));
  whi[i] = (ushort_t)hb;
  wlo[i] = (ushort_t)lb;
}

// pack KNN features into frag-major split-bf16 planes with norm augmentation.
__global__ void packknn_k(const float* __restrict__ xf, const float* __restrict__ nr,
                          ushort_t* __restrict__ ahi, ushort_t* __restrict__ alo,
                          ushort_t* __restrict__ bhi, ushort_t* __restrict__ blo){
  int i = blockIdx.x*256 + threadIdx.x;
  if (i >= NTILE*5*64*8) return;
  int e = i & 7;
  int lane = (i >> 3) & 63;
  int rest = i >> 9;
  int kc = rest % 5, jt = rest / 5;
  int n = jt*32 + (lane & 31);
  int k = kc*16 + (lane >> 5)*8 + e;
  float f = (k < 64) ? xf[(size_t)n*227 + 35 + k] : 0.f;
  float av, bv;
  if (k < 64)      { av = 2.f*f;   bv = f; }
  else if (k == 64){ av = nr[n];   bv = -1.f; }
  else if (k == 65){ av = 1.f;     bv = -nr[n]; }
  else             { av = 0.f;     bv = 0.f; }
  uint ah = f2bf_bits(av); uint al = f2bf_bits(av - __uint_as_float(ah<<16));
  uint bh = f2bf_bits(bv); uint bl = f2bf_bits(bv - __uint_as_float(bh<<16));
  ahi[i] = (ushort_t)ah; alo[i] = (ushort_t)al;
  bhi[i] = (ushort_t)bh; blo[i] = (ushort_t)bl;
}

__global__ void fillmark_k(bf16* __restrict__ out, int n){
  int i = blockIdx.x*256 + threadIdx.x;
  if (i < n) out[i] = __float2bfloat16(12345.0f);
}

// ---------------------------------------------------------------------------
// Single-layer split-bf16 MFMA GEMM (validated round 8): 128-col panels,
// acc[2], K-chunked 32 KB slab. Used for fc1's 192->384 and 384->256.
// ---------------------------------------------------------------------------
template<int ACT>
__global__ __launch_bounds__(256) void gemm_mfma_k(
    const float* __restrict__ A, int lda, int K, int M,
    const ushort_t* __restrict__ wh, const ushort_t* __restrict__ wl,
    int woff, int KqTot,
    const float* __restrict__ scale, const float* __restrict__ shift,
    float* __restrict__ C, int ldc, int N)
{
  __shared__ __align__(16) uint slab[64*128];   // 32768 B
  const int tid = threadIdx.x;
  const int lane = tid & 63;
  const int wv = tid >> 6;
  const int np = lane & 31;
  const int hb2 = lane >> 5;
  const int rhalf = wv & 1, thalf = wv >> 1;
  const int rb = blockIdx.x * 64;
  const int tbase = blockIdx.y * 4;
  const int row_l = rhalf*32 + np;
  int NtLoc = (N >> 5) - tbase; if (NtLoc > 4) NtLoc = 4;

  Acc16 acc[2];
#pragma unroll
  for (int u=0;u<2;u++)
#pragma unroll
    for (int i=0;i<16;i++) acc[u].f[i] = 0.f;

#pragma unroll 1
  for (int k0 = 0; k0 < K; k0 += 128) {
    for (int e = tid; e < 64*32; e += 256) {
      int r = e >> 5, g = e & 31;
      int gr = rb + r;
      uint p[4];
#pragma unroll
      for (int u=0;u<4;u++){
        int k = k0 + g*4 + u;
        float f = (gr < M && k < K) ? A[(size_t)gr*lda + k] : 0.f;
        uint hb = f2bf_bits(f);
        uint lb = f2bf_bits(f - __uint_as_float(hb<<16));
        p[u] = (hb<<16) | lb;
      }
      *(uint4*)&slab[r*128 + (((g ^ r) & 31)<<2)] = make_uint4(p[0],p[1],p[2],p[3]);
    }
    __syncthreads();
    int qb = k0 >> 5;
    int KqLoc = KqTot - qb; if (KqLoc > 4) KqLoc = 4;
#pragma unroll 1
    for (int q = 0; q < KqLoc; q++){
#pragma unroll
      for (int ks = 0; ks < 2; ks++){
        int g0 = q*8 + ks*4 + hb2*2;
        uint4 a0 = *(const uint4*)&slab[row_l*128 + ((((g0  ) ^ row_l) & 31)<<2)];
        uint4 a1 = *(const uint4*)&slab[row_l*128 + ((((g0+1) ^ row_l) & 31)<<2)];
        uint au[8] = {a0.x,a0.y,a0.z,a0.w,a1.x,a1.y,a1.z,a1.w};
        FragAB ah, al;
#pragma unroll
        for (int p=0;p<4;p++){
          ah.u[p] = (au[2*p]>>16)     | (au[2*p+1] & 0xFFFF0000u);
          al.u[p] = (au[2*p]&0xFFFFu) | (au[2*p+1]<<16);
        }
#pragma unroll
        for (int u=0;u<2;u++){
          int t = thalf + u*2;
          if (t < NtLoc){
            size_t fb = (size_t)woff + ((size_t)(((tbase+t)*KqTot + qb + q)*2 + ks))*512 + (size_t)lane*8;
            FragB bh, bl;
            bh.q = *(const uint4*)(wh + fb);
            bl.q = *(const uint4*)(wl + fb);
            acc[u].v = __builtin_amdgcn_mfma_f32_32x32x16_bf16(ah.v, bh.v, acc[u].v, 0,0,0);
            acc[u].v = __builtin_amdgcn_mfma_f32_32x32x16_bf16(al.v, bh.v, acc[u].v, 0,0,0);
            acc[u].v = __builtin_amdgcn_mfma_f32_32x32x16_bf16(ah.v, bl.v, acc[u].v, 0,0,0);
          }
        }
      }
    }
    __syncthreads();
  }

#pragma unroll
  for (int u=0;u<2;u++){
    int t = thalf + u*2;
    if (t < NtLoc){
      int col = (tbase+t)*32 + np;
      float scv = scale[col], shv = shift[col];
#pragma unroll
      for (int reg=0;reg<16;reg++){
        int r32 = (reg&3) + 8*(reg>>2) + 4*hb2;
        int gr = rb + rhalf*32 + r32;
        if (gr < M){
          float v = acc[u].f[reg]*scv + shv;
          if (ACT==1) v = v > 0.f ? v : 0.2f*v;
          C[(size_t)gr*ldc + col] = v;
        }
      }
    }
  }
}

// ---------------------------------------------------------------------------
// Generic fused per-row MLP (validated round 9): up to 6 layers, dims <= 256.
// ---------------------------------------------------------------------------
struct MLayer { int K, N, Kq, Nt, woff, soff, hoff, epi, act; float gmul; };
struct MCfg { MLayer L[6]; };

template<int NL, int OUTMODE>
__global__ __launch_bounds__(256) void mlp_fused_k(
    const float* __restrict__ A0, int lda0, int K0, int M,
    MCfg cfg,
    const ushort_t* __restrict__ wh, const ushort_t* __restrict__ wl,
    const float* __restrict__ wc,
    float* __restrict__ Cout, int ldc,
    void* __restrict__ oflg, const int* __restrict__ flag)
{
  __shared__ __align__(16) uint slab[64*256];   // 65536 B
  const int tid = threadIdx.x;
  const int lane = tid & 63;
  const int wv = tid >> 6;
  const int np = lane & 31;
  const int hb2 = lane >> 5;
  const int rhalf = wv & 1, thalf = wv >> 1;
  const int rb = blockIdx.x * 64;
  const int row_l = rhalf*32 + np;

  for (int e = tid; e < 64*64; e += 256) {
    int r = e >> 6, g = e & 63;
    int gr = rb + r;
    uint p[4];
#pragma unroll
    for (int u=0;u<4;u++){
      int k = g*4+u;
      float f = (gr < M && k < K0) ? A0[(size_t)gr*lda0 + k] : 0.f;
      uint hb = f2bf_bits(f);
      uint lb = f2bf_bits(f - __uint_as_float(hb<<16));
      p[u] = (hb<<16) | lb;
    }
    *(uint4*)&slab[r*256 + (((g ^ r) & 63)<<2)] = make_uint4(p[0],p[1],p[2],p[3]);
  }
  __syncthreads();

#pragma unroll 1
  for (int l = 0; l < NL; l++){
    const int N = cfg.L[l].N, Kq = cfg.L[l].Kq, Nt = cfg.L[l].Nt;
    const int woff = cfg.L[l].woff, soff = cfg.L[l].soff, hoff = cfg.L[l].hoff;
    const int epi = cfg.L[l].epi, actf = cfg.L[l].act;
    const float gmul = cfg.L[l].gmul;
    Acc16 acc[4];
#pragma unroll
    for (int u=0;u<4;u++)
#pragma unroll
      for (int i=0;i<16;i++) acc[u].f[i] = 0.f;

#pragma unroll 1
    for (int q = 0; q < Kq; q++){
#pragma unroll
      for (int ks = 0; ks < 2; ks++){
        int g0 = (q*32 + ks*16 + hb2*8) >> 2;
        uint4 a0 = *(const uint4*)&slab[row_l*256 + ((((g0  ) ^ row_l) & 63)<<2)];
        uint4 a1 = *(const uint4*)&slab[row_l*256 + ((((g0+1) ^ row_l) & 63)<<2)];
        uint au[8] = {a0.x,a0.y,a0.z,a0.w,a1.x,a1.y,a1.z,a1.w};
        FragAB ah, al;
#pragma unroll
        for (int p=0;p<4;p++){
          ah.u[p] = (au[2*p]>>16)     | (au[2*p+1] & 0xFFFF0000u);
          al.u[p] = (au[2*p]&0xFFFFu) | (au[2*p+1]<<16);
        }
#pragma unroll
        for (int u=0;u<4;u++){
          int t = thalf + u*2;
          if (t < Nt){
            size_t fb = (size_t)woff + ((size_t)((t*Kq + q)*2 + ks))*512 + (size_t)lane*8;
            FragB bh, bl;
            bh.q = *(const uint4*)(wh + fb);
            bl.q = *(const uint4*)(wl + fb);
            acc[u].v = __builtin_amdgcn_mfma_f32_32x32x16_bf16(ah.v, bh.v, acc[u].v, 0,0,0);
            acc[u].v = __builtin_amdgcn_mfma_f32_32x32x16_bf16(al.v, bh.v, acc[u].v, 0,0,0);
            acc[u].v = __builtin_amdgcn_mfma_f32_32x32x16_bf16(ah.v, bl.v, acc[u].v, 0,0,0);
          }
        }
      }
    }
    __syncthreads();
#pragma unroll
    for (int u=0;u<4;u++){
      int t = thalf + u*2;
      if (t < Nt){
        int col = t*32 + np;
        if (col < N){
          float scv = (epi==0) ? wc[soff+col] : 0.f;
          float shv = wc[hoff+col];
#pragma unroll
          for (int reg=0;reg<16;reg++){
            int r32 = (reg&3) + 8*(reg>>2) + 4*hb2;
            float v = acc[u].f[reg];
            if (epi==0)      v = v*scv + shv;
            else if (epi==1) v = v + shv;
            else             v = (v + shv)*gmul;
            if (actf==1)      v = v > 0.f ? v : 0.2f*v;
            else if (actf==2) v = __sinf(v);
            if (l == NL-1){
              int gr = rb + rhalf*32 + r32;
              if (gr < M){
                if (OUTMODE==0) Cout[(size_t)gr*ldc + col] = v;
                else {
                  if (!(fabsf(v) < 1e30f)) v = 777.0f;  // canary
                  size_t oi = (size_t)gr*3 + col;
                  if (flag[0]) ((bf16*)oflg)[oi] = __float2bfloat16(v);
                  else         ((float*)oflg)[oi] = v;
                }
              }
            } else {
              int r = rhalf*32 + r32;
              uint hb = f2bf_bits(v);
              uint lb = f2bf_bits(v - __uint_as_float(hb<<16));
              slab[r*256 + ((((col>>2) ^ r) & 63)<<2) + (col&3)] = (hb<<16) | lb;
            }
          }
        }
      }
    }
    __syncthreads();
  }
}

// ---------------------------------------------------------------------------
// Edge-conv MLP with FUSED GATHER staging (validated round 12): stages
// cat(xf[j]-xf[n], xf[n]) directly from x_feat using the knn index — no
// intermediate edge buffer. Compute/epilogue identical to mlp_fused (OUT=0).
// ---------------------------------------------------------------------------
template<int NL>
__global__ __launch_bounds__(256) void mlp_edge_k(
    const float* __restrict__ xf, int coff, int CIN,
    const int* __restrict__ idx, int n0, int M /*edges*/,
    MCfg cfg,
    const ushort_t* __restrict__ wh, const ushort_t* __restrict__ wl,
    const float* __restrict__ wc,
    float* __restrict__ Cout, int ldc)
{
  __shared__ __align__(16) uint slab[64*256];   // 65536 B
  const int tid = threadIdx.x;
  const int lane = tid & 63;
  const int wv = tid >> 6;
  const int np = lane & 31;
  const int hb2 = lane >> 5;
  const int rhalf = wv & 1, thalf = wv >> 1;
  const int rb = blockIdx.x * 64;
  const int row_l = rhalf*32 + np;
  const int W2 = 2*CIN;

  for (int e = tid; e < 64*64; e += 256) {
    int r = e >> 6, g = e & 63;
    int ek = rb + r;
    int n = 0, j = 0;
    bool ok = (ek < M);
    if (ok){
      n = n0 + ek/KNN_K;
      j = idx[n*KNN_K + ek%KNN_K];
    }
    uint p[4];
#pragma unroll
    for (int u=0;u<4;u++){
      int k = g*4+u;
      float f = 0.f;
      if (ok && k < W2){
        f = (k < CIN) ? xf[(size_t)j*227 + coff + k] - xf[(size_t)n*227 + coff + k]
                      : xf[(size_t)n*227 + coff + (k-CIN)];
      }
      uint hb = f2bf_bits(f);
      uint lb = f2bf_bits(f - __uint_as_float(hb<<16));
      p[u] = (hb<<16) | lb;
    }
    *(uint4*)&slab[r*256 + (((g ^ r) & 63)<<2)] = make_uint4(p[0],p[1],p[2],p[3]);
  }
  __syncthreads();

#pragma unroll 1
  for (int l = 0; l < NL; l++){
    const int N = cfg.L[l].N, Kq = cfg.L[l].Kq, Nt = cfg.L[l].Nt;
    const int woff = cfg.L[l].woff, soff = cfg.L[l].soff, hoff = cfg.L[l].hoff;
    const int epi = cfg.L[l].epi, actf = cfg.L[l].act;
    Acc16 acc[4];
#pragma unroll
    for (int u=0;u<4;u++)
#pragma unroll
      for (int i=0;i<16;i++) acc[u].f[i] = 0.f;

#pragma unroll 1
    for (int q = 0; q < Kq; q++){
#pragma unroll
      for (int ks = 0; ks < 2; ks++){
        int g0 = (q*32 + ks*16 + hb2*8) >> 2;
        uint4 a0 = *(const uint4*)&slab[row_l*256 + ((((g0  ) ^ row_l) & 63)<<2)];
        uint4 a1 = *(const uint4*)&slab[row_l*256 + ((((g0+1) ^ row_l) & 63)<<2)];
        uint au[8] = {a0.x,a0.y,a0.z,a0.w,a1.x,a1.y,a1.z,a1.w};
        FragAB ah, al;
#pragma unroll
        for (int p=0;p<4;p++){
          ah.u[p] = (au[2*p]>>16)     | (au[2*p+1] & 0xFFFF0000u);
          al.u[p] = (au[2*p]&0xFFFFu) | (au[2*p+1]<<16);
        }
#pragma unroll
        for (int u=0;u<4;u++){
          int t = thalf + u*2;
          if (t < Nt){
            size_t fb = (size_t)woff + ((size_t)((t*Kq + q)*2 + ks))*512 + (size_t)lane*8;
            FragB bh, bl;
            bh.q = *(const uint4*)(wh + fb);
            bl.q = *(const uint4*)(wl + fb);
            acc[u].v = __builtin_amdgcn_mfma_f32_32x32x16_bf16(ah.v, bh.v, acc[u].v, 0,0,0);
            acc[u].v = __builtin_amdgcn_mfma_f32_32x32x16_bf16(al.v, bh.v, acc[u].v, 0,0,0);
            acc[u].v = __builtin_amdgcn_mfma_f32_32x32x16_bf16(ah.v, bl.v, acc[u].v, 0,0,0);
          }
        }
      }
    }
    __syncthreads();
#pragma unroll
    for (int u=0;u<4;u++){
      int t = thalf + u*2;
      if (t < Nt){
        int col = t*32 + np;
        if (col < N){
          float scv = (epi==0) ? wc[soff+col] : 0.f;
          float shv = wc[hoff+col];
#pragma unroll
          for (int reg=0;reg<16;reg++){
            int r32 = (reg&3) + 8*(reg>>2) + 4*hb2;
            float v = acc[u].f[reg];
            if (epi==0)      v = v*scv + shv;
            else             v = v + shv;
            if (actf==1)     v = v > 0.f ? v : 0.2f*v;
            if (l == NL-1){
              int gr = rb + rhalf*32 + r32;
              if (gr < M) Cout[(size_t)gr*ldc + col] = v;
            } else {
              int r = rhalf*32 + r32;
              uint hb = f2bf_bits(v);
              uint lb = f2bf_bits(v - __uint_as_float(hb<<16));
              slab[r*256 + ((((col>>2) ^ r) & 63)<<2) + (col&3)] = (hb<<16) | lb;
            }
          }
        }
      }
    }
    __syncthreads();
  }
}

// ---------------------------------------------------------------------------
// MFMA KNN (validated round 7).
// ---------------------------------------------------------------------------
#define INS5(tv, tj, v, j) \
  if ((v) > tv[4]){ tv[4]=(v); tj[4]=(j); \
    _Pragma("unroll") \
    for (int q=4;q>0;q--) \
      if (tv[q] > tv[q-1]){ float tf=tv[q-1]; tv[q-1]=tv[q]; tv[q]=tf; \
                            int ti=tj[q-1]; tj[q-1]=tj[q]; tj[q]=ti; } }

__global__ __launch_bounds__(256) void knn_mfma_k(
    const ushort_t* __restrict__ ahi, const ushort_t* __restrict__ alo,
    const ushort_t* __restrict__ bhi, const ushort_t* __restrict__ blo,
    int* __restrict__ out)
{
  __shared__ float mv[4][32][5];
  __shared__ int   mjj[4][32][5];
  const int tid = threadIdx.x;
  const int lane = tid & 63;
  const int wv = tid >> 6;
  const int np = lane & 31;
  const int hb2 = lane >> 5;
  const int it = blockIdx.x;
  const int ig = it*32 + np;

  FragB vh[5], vl[5];
  {
    size_t bb = (size_t)(it*5)*512 + (size_t)lane*8;
#pragma unroll
    for (int kc=0;kc<5;kc++){
      vh[kc].q = *(const uint4*)(bhi + bb + kc*512);
      vl[kc].q = *(const uint4*)(blo + bb + kc*512);
    }
  }

  float tv[5] = {-1e30f,-1e30f,-1e30f,-1e30f,-1e30f};
  int   tj[5] = {0,0,0,0,0};

  FragB uh[5], ul[5], nh[5], nl[5];
  {
    size_t ab = (size_t)(wv*5)*512 + (size_t)lane*8;
#pragma unroll
    for (int kc=0;kc<5;kc++){
      uh[kc].q = *(const uint4*)(ahi + ab + kc*512);
      ul[kc].q = *(const uint4*)(alo + ab + kc*512);
    }
  }

#pragma unroll 1
  for (int t = 0; t < NTILE/4; t++){
    int jt = wv + t*4;
    if (t+1 < NTILE/4){
      size_t an = (size_t)((jt+4)*5)*512 + (size_t)lane*8;
#pragma unroll
      for (int kc=0;kc<5;kc++){
        nh[kc].q = *(const uint4*)(ahi + an + kc*512);
        nl[kc].q = *(const uint4*)(alo + an + kc*512);
      }
    }
    Acc16 acc;
#pragma unroll
    for (int q=0;q<16;q++) acc.f[q] = 0.f;
#pragma unroll
    for (int kc=0;kc<5;kc++){
      acc.v = __builtin_amdgcn_mfma_f32_32x32x16_bf16(uh[kc].v, vh[kc].v, acc.v, 0,0,0);
      acc.v = __builtin_amdgcn_mfma_f32_32x32x16_bf16(ul[kc].v, vh[kc].v, acc.v, 0,0,0);
      acc.v = __builtin_amdgcn_mfma_f32_32x32x16_bf16(uh[kc].v, vl[kc].v, acc.v, 0,0,0);
    }
    int jb = jt*32 + 4*hb2;
#pragma unroll
    for (int reg=0;reg<16;reg++){
      int j = jb + (reg&3) + 8*(reg>>2);
      float v = acc.f[reg];
      if (j != ig) { INS5(tv, tj, v, j); }
    }
    if (t+1 < NTILE/4){
#pragma unroll
      for (int kc=0;kc<5;kc++){ uh[kc] = nh[kc]; ul[kc] = nl[kc]; }
    }
  }

#pragma unroll
  for (int s=0;s<5;s++){
    float ov = __shfl_xor(tv[s], 32, 64);
    int   oj = __shfl_xor(tj[s], 32, 64);
    INS5(tv, tj, ov, oj);
  }
  if (hb2 == 0){
#pragma unroll
    for (int s=0;s<5;s++){ mv[wv][np][s] = tv[s]; mjj[wv][np][s] = tj[s]; }
  }
  __syncthreads();
  if (tid < 32){
    float bv[5]; int bj[5];
#pragma unroll
    for (int s=0;s<5;s++){ bv[s] = mv[0][tid][s]; bj[s] = mjj[0][tid][s]; }
#pragma unroll
    for (int w=1;w<4;w++)
#pragma unroll
      for (int s=0;s<5;s++){
        float v = mv[w][tid][s]; int j = mjj[w][tid][s];
        INS5(bv, bj, v, j);
      }
    int gi = it*32 + tid;
#pragma unroll
    for (int s=0;s<5;s++) out[gi*KNN_K + s] = bj[s];
  }
}

// ---------------------------------------------------------------------------
// Fused 8-layer SIREN + head (v9, validated round 11): register-resident acts
// + sigma-fold + 1/2pi-folded weights -> raw v_sin. One barrier.
// ---------------------------------------------------------------------------
__global__ __launch_bounds__(256) void siren_fused_k(
    const void* __restrict__ upin,
    const ushort_t* __restrict__ wf16,
    const float* __restrict__ W0c, const float* __restrict__ S0c, const float* __restrict__ H0c,
    const float* __restrict__ HRc,
    const float* __restrict__ WFc, const float* __restrict__ BFc,
    float* __restrict__ logits, const int* __restrict__ flag)
{
  __shared__ float intile[4*32*8];                   // 4096 B
  __shared__ __align__(16) float w0s[128*8];         // 4096 B (scale*inv2pi, bias slot 7)
  __shared__ __align__(16) float hrs[7*128];         // 3584 B biases * inv2pi
  __shared__ __align__(16) float wfs[128];
  __shared__ float bfs[1];

  const int tid  = threadIdx.x;
  const int lane = tid & 63;
  const int wv   = tid >> 6;
  const int np   = lane & 31;
  const int hb2  = lane >> 5;
  const int rowbase = blockIdx.x * 128 + wv * 32;
  const int isbf = flag[0];
  float* intw = intile + wv*32*8;

  for (int e = tid; e < 128*7; e += 256){
    int c = e/7, k = e%7;
    w0s[c*8+k] = W0c[e]*S0c[c]*INV2PI;
  }
  if (tid < 128) w0s[tid*8+7] = H0c[tid]*INV2PI;
  for (int e = tid; e < 7*128; e += 256) hrs[e] = HRc[e]*INV2PI;
  if (tid < 128) wfs[tid] = WFc[tid];
  if (tid == 0) bfs[0] = BFc[0];
  for (int e = lane; e < 32*7; e += 64) {
    int r = e/7, k = e%7;
    int gr = rowbase + r;
    float v = 0.f;
    if (gr < UP_ROWS)
      v = isbf ? b2f(((const bf16*)upin)[(size_t)gr*7+k]) : ((const float*)upin)[(size_t)gr*7+k];
    intw[r*8+k] = v;
  }
  __syncthreads();   // staged tables ready; ONLY barrier in the kernel

  uint st0[16], st1[16];   // per group: [j0,j1] and [j2,j3] packed fp16
  {
    float xin[7];
#pragma unroll
    for (int k=0;k<7;k++) xin[k] = intw[np*8+k];
#pragma unroll
    for (int g = 0; g < 16; g++){
      float xs[4];
#pragma unroll
      for (int j = 0; j < 4; j++){
        int c = g*8 + hb2*4 + j;
        const float4 wa = *(const float4*)&w0s[c*8];
        const float4 wb = *(const float4*)&w0s[c*8+4];
        float a = wb.w;                     // bias (pre-scaled)
        a += xin[0]*wa.x; a += xin[1]*wa.y; a += xin[2]*wa.z; a += xin[3]*wa.w;
        a += xin[4]*wb.x; a += xin[5]*wb.y; a += xin[6]*wb.z;
        xs[j] = sinrev(a);
      }
      H2U u0,u1;
      u0.h = __builtin_amdgcn_cvt_pkrtz(xs[0],xs[1]);
      u1.h = __builtin_amdgcn_cvt_pkrtz(xs[2],xs[3]);
      st0[g] = u0.u; st1[g] = u1.u;
    }
  }

  FragH fr[8];
#pragma unroll
  for (int m = 0; m < 8; m++)
    fr[m].q = make_uint4(st0[2*m], st1[2*m], st0[2*m+1], st1[2*m+1]);

  uint nst0[16], nst1[16];
#pragma unroll 1
  for (int l = 0; l < 7; l++) {
#pragma unroll
    for (int tp = 0; tp < 2; tp++){
      Acc16 acc0, acc1;
#pragma unroll
      for (int i=0;i<16;i++){ acc0.f[i] = 0.f; acc1.f[i] = 0.f; }
#pragma unroll
      for (int m = 0; m < 8; m++){
        int fb = (((l*8 + m)*4 + tp*2) << 9) + lane*8;
        FragH bh0, bh1;
        bh0.q = *(const uint4*)(wf16 + fb);
        bh1.q = *(const uint4*)(wf16 + fb + 512);
        acc0.v = __builtin_amdgcn_mfma_f32_32x32x16_f16(bh0.v, fr[m].v, acc0.v, 0,0,0);
        acc1.v = __builtin_amdgcn_mfma_f32_32x32x16_f16(bh1.v, fr[m].v, acc1.v, 0,0,0);
      }
#pragma unroll
      for (int rg = 0; rg < 4; rg++){
        int g0 = (tp*2+0)*4 + rg;
        const float4 b0v = *(const float4*)&hrs[l*128 + g0*8 + hb2*4];
        float x0 = sinrev(acc0.f[rg*4+0] + b0v.x);
        float x1 = sinrev(acc0.f[rg*4+1] + b0v.y);
        float x2 = sinrev(acc0.f[rg*4+2] + b0v.z);
        float x3 = sinrev(acc0.f[rg*4+3] + b0v.w);
        H2U u0,u1;
        u0.h = __builtin_amdgcn_cvt_pkrtz(x0,x1);
        u1.h = __builtin_amdgcn_cvt_pkrtz(x2,x3);
        nst0[g0] = u0.u; nst1[g0] = u1.u;

        int g1 = (tp*2+1)*4 + rg;
        const float4 b1v = *(const float4*)&hrs[l*128 + g1*8 + hb2*4];
        float y0 = sinrev(acc1.f[rg*4+0] + b1v.x);
        float y1 = sinrev(acc1.f[rg*4+1] + b1v.y);
        float y2 = sinrev(acc1.f[rg*4+2] + b1v.z);
        float y3 = sinrev(acc1.f[rg*4+3] + b1v.w);
        H2U v0,v1;
        v0.h = __builtin_amdgcn_cvt_pkrtz(y0,y1);
        v1.h = __builtin_amdgcn_cvt_pkrtz(y2,y3);
        nst0[g1] = v0.u; nst1[g1] = v1.u;
      }
    }
    if (l < 6){
#pragma unroll
      for (int m = 0; m < 8; m++)
        fr[m].q = make_uint4(nst0[2*m], nst1[2*m], nst0[2*m+1], nst1[2*m+1]);
    }
  }

  {
    float a = 0.f;
#pragma unroll
    for (int g = 0; g < 16; g++){
      const float4 w4 = *(const float4*)&wfs[g*8 + hb2*4];
      H2U u0,u1; u0.u = nst0[g]; u1.u = nst1[g];
      a += (float)u0.h.x*w4.x + (float)u0.h.y*w4.y
         + (float)u1.h.x*w4.z + (float)u1.h.y*w4.w;
    }
    a += __shfl_xor(a, 32, 64);
    int gr = rowbase + np;
    if (hb2 == 0 && gr < UP_ROWS) logits[gr] = a + bfs[0];
  }
}

// ---------------------------------------------------------------------------
__global__ void featin_k(const void* __restrict__ ldx, const void* __restrict__ pos,
                         float* __restrict__ xf, const int* __restrict__ flag){
  int i = blockIdx.x*256 + threadIdx.x;
  if (i >= N_PTS*35) return;
  int n = i / 35, c = i % 35;
  float v;
  if (flag[0]) {
    v = (c < 3) ? b2f(((const bf16*)ldx)[n*3+c]) : b2f(((const bf16*)pos)[n*32 + (c-3)]);
  } else {
    v = (c < 3) ? ((const float*)ldx)[n*3+c] : ((const float*)pos)[n*32 + (c-3)];
  }
  xf[(size_t)n*227 + c] = v;
}

// kmax with separate element stride (ld)
__global__ void kmax_k(const float* __restrict__ e2, int C, int ld, float* __restrict__ f1,
                       int n0, int np){
  int i = blockIdx.x*256 + threadIdx.x;
  if (i >= np*C) return;
  int nl = i / C, c = i % C;
  float v = -1e30f;
  for (int k=0;k<KNN_K;k++) v = fmaxf(v, e2[((size_t)nl*KNN_K+k)*ld + c]);
  f1[(size_t)(n0+nl)*C + c] = v;
}

template<int C>
__global__ __launch_bounds__(256) void reduce1_k(const float* __restrict__ X, int n,
                                                 float* __restrict__ pmax, float* __restrict__ psum){
  const int tid = threadIdx.x;
  const int c = tid % C;
  const int r0 = tid / C;
  const int TPR = 256 / C;
  float vmax = -1e30f, vsum = 0.f;
  for (int row = blockIdx.x * TPR + r0; row < n; row += gridDim.x * TPR) {
    float v = X[(size_t)row * C + c];
    vmax = fmaxf(vmax, v); vsum += v;
  }
  __shared__ float smax[256], ssum[256];
  smax[tid]=vmax; ssum[tid]=vsum;
  __syncthreads();
  if (tid < C) {
    for (int q=1;q<TPR;q++){ vmax=fmaxf(vmax, smax[q*C+c]); vsum += ssum[q*C+c]; }
    pmax[blockIdx.x*C + c] = vmax; psum[blockIdx.x*C + c] = vsum;
  }
}

// merged reduce2 + foldshift
template<int C>
__global__ __launch_bounds__(256) void red2fold_k(
    const float* __restrict__ pmax, const float* __restrict__ psum,
    int nblk, float invn,
    const float* __restrict__ W, int ldw, int off1, int off2,
    const float* __restrict__ scale, const float* __restrict__ shift,
    float* __restrict__ out, int N)
{
  __shared__ float smax[C], ssum[C];
  int tid = threadIdx.x;
  if (tid < C){
    float vmax=-1e30f, vsum=0.f;
    for (int b=0;b<nblk;b++){ vmax=fmaxf(vmax,pmax[b*C+tid]); vsum+=psum[b*C+tid]; }
    smax[tid]=vmax; ssum[tid]=vsum*invn;
  }
  __syncthreads();
  for (int n = tid; n < N; n += 256){
    const float* wr = W + (size_t)n*ldw;
    float s = 0.f;
    for (int j=0;j<C;j++) s += wr[off1+j]*smax[j];
    for (int j=0;j<C;j++) s += wr[off2+j]*ssum[j];
    out[n] = s*scale[n] + shift[n];
  }
}

// varying-channels-only concat (fmax/favg folded into shift vectors)
__global__ void concat2_k(const float* __restrict__ xf, int coff, int CF,
                          const float* __restrict__ f1, int C,
                          float* __restrict__ h, int n0, int np){
  int W = CF + C;
  int i = blockIdx.x*256 + threadIdx.x;
  if (i >= np*W) return;
  int nl = i / W, c = i % W;
  int n = n0 + nl;
  float v = (c < CF) ? xf[(size_t)n*227 + coff + c] : f1[(size_t)n*C + (c-CF)];
  h[(size_t)nl*W + c] = v;
}

__global__ void norms_k(const float* __restrict__ xf, float* __restrict__ nr){
  int n = blockIdx.x*256 + threadIdx.x;
  if (n >= N_PTS) return;
  const float* p = xf + (size_t)n*227 + 35;
  float s = 0.f;
  for (int d=0;d<64;d++) s += p[d]*p[d];
  nr[n] = s;
}

// 4 points per 256-thread block (one per wave) — validated round 11.
__global__ __launch_bounds__(256) void softgather_k(const float* __restrict__ logits,
                                                    const int* __restrict__ up_idx,
                                                    const float* __restrict__ xf,
                                                    float* __restrict__ z){
  __shared__ float lw[4][KUP]; __shared__ int li[4][KUP];
  int sub = threadIdx.x >> 6;
  int tid = threadIdx.x & 63;
  int m = blockIdx.x*4 + sub;
  bool ok = (m < M_PTS);
  if (ok && tid < KUP){
    lw[sub][tid] = logits[(size_t)m*KUP + tid];
    li[sub][tid] = up_idx[(size_t)m*KUP + tid];
  }
  __syncthreads();
  if (ok){
    float mx = -1e30f;
    for (int k=0;k<KUP;k++) mx = fmaxf(mx, lw[sub][k]);
    float w[KUP]; float s = 0.f;
    for (int k=0;k<KUP;k++){ w[k] = expf(lw[sub][k]-mx); s += w[k]; }
    float inv = 1.f/s;
    for (int c = tid; c < 227; c += 64){
      float acc = 0.f;
      for (int k=0;k<KUP;k++) acc += w[k] * xf[(size_t)li[sub][k]*227 + c];
      z[(size_t)m*227 + c] = acc*inv;
    }
  }
}

// ---------------------------------------------------------------------------
extern "C" void kernel_launch(void* const* d_in, const int* in_sizes, int n_in,
                              void* d_out, int out_size, void* d_ws, size_t ws_size,
                              hipStream_t stream) {
  const int *idx0  = (const int*)d_in[3];
  const int *upidx = (const int*)d_in[37];

  // ---- workspace layout (floats) ----
  float* ws = (float*)d_ws;
  float* x_feat = ws;                     // [N,227]
  float* f1b    = ws + 3602944;           // [N,128]
  float* pmax   = ws + 5634560;           // [256*128]
  float* psum   = ws + 5667328;           // [256*128]
  float* fold0  = pmax + 24576;           // [192]
  float* fold1  = psum + 24576;           // [384]
  int*   flag   = (int*)(ws + 5700352);
  int*   idx1   = (int*)(ws + 5700368);   // N*5
  float* nrm    = ws + 5779728;           // N
  float* logits = ws + 5795600;           // UP_ROWS
  float* wcvt   = ws + 6508352;           // 706,020 fp32 weights
  float* S      = ws + 7214400;           // scratch arena (9,662,464 floats)
  ushort_t* whi  = (ushort_t*)(S + 9662464);  // siren fp16 plane (114688)
  ushort_t* wlo  = whi + 114688;
  ushort_t* gwhi = wlo + 114688;              // mlp planes (503808 each)
  ushort_t* gwlo = gwhi + 503808;

  const size_t NEED = (size_t)(7214400 + 9662464) * 4
                    + (size_t)(114688*2 + 503808*2) * 2;   // ~70.0 MB
  if (ws_size < NEED) {
    fillmark_k<<<CDIV(out_size,256),256,0,stream>>>((bf16*)d_out, out_size);
    return;
  }

  // ---- dtype flag + one-shot weight conversion to fp32 ----
  flag_k<<<1,64,0,stream>>>((const uint*)d_in[2], flag);
  CvtTab tab;
  int wcoff = 0, seg = 0;
  auto CVT = [&](int i, int n)->const float* {
    tab.src[seg] = d_in[i]; tab.start[seg] = wcoff; seg++;
    const float* p = wcvt + wcoff; wcoff += n;
    return p;
  };
  const float *E0W1=CVT(4,8960),  *E0S1=CVT(5,128),  *E0H1=CVT(6,128),
              *E0W2=CVT(7,8192),  *E0B2=CVT(8,64);
  const float *F0W1=CVT(9,43584), *F0S1=CVT(10,192), *F0H1=CVT(11,192),
              *F0W2=CVT(12,24576),*F0S2=CVT(13,128), *F0H2=CVT(14,128),
              *F0W3=CVT(15,8192), *F0S3=CVT(16,64),  *F0H3=CVT(17,64),
              *F0W4=CVT(18,4096), *F0B4=CVT(19,64);
  const float *E1W1=CVT(20,32768),*E1S1=CVT(21,256), *E1H1=CVT(22,256),
              *E1W2=CVT(23,32768),*E1B2=CVT(24,128);
  const float *F1W1=CVT(25,172032),*F1S1=CVT(26,384),*F1H1=CVT(27,384),
              *F1W2=CVT(28,98304),*F1S2=CVT(29,256), *F1H2=CVT(30,256),
              *F1W3=CVT(31,32768),*F1S3=CVT(32,128), *F1H3=CVT(33,128),
              *F1W4=CVT(34,16384),*F1B4=CVT(35,128);
  const float *UPW0=CVT(38,896),  *UPS0=CVT(39,128), *UPH0=CVT(40,128),
              *UPWR=CVT(41,114688),*UPSR=CVT(42,896),*UPHR=CVT(43,896),
              *UPWF=CVT(44,128),  *UPBF=CVT(45,1);
  const float *DW0=CVT(46,58112), *DB0=CVT(47,256),
              *DW1=CVT(48,32768), *DB1=CVT(49,128),
              *DW2=CVT(50,8192),  *DB2=CVT(51,64),
              *DW3=CVT(52,2048),  *DB3=CVT(53,32),
              *DW4=CVT(54,512),   *DB4=CVT(55,16),
              *DWF=CVT(56,48),    *DBF=CVT(57,3);
  cvt_all_k<<<CDIV(wcoff,256),256,0,stream>>>(tab, wcvt, flag, wcoff);

  // siren fp16 plane (scale + 1/2pi + sigma folded)
  packfrag16_k<<<CDIV(114688,256),256,0,stream>>>(UPWR, UPSR, whi, 114688);

  // mlp planes in ONE batched launch
  PackTab ptab;
  int offs[18];
  int ptotal = 0;
  {
    int q = 0;
    auto REG = [&](const float* s, int N, int K, int ldk, int Kpad){
      ptab.src[q]=s; ptab.N[q]=N; ptab.K[q]=K; ptab.ldk[q]=ldk; ptab.Kpad[q]=Kpad;
      ptab.start[q]=ptotal; offs[q]=ptotal;
      ptotal += CDIV(N,32)*32*Kpad; q++;
    };
    REG(F0W1,192, 99,227,128);                         // const-folded K
    REG(F0W2,128,192,192,192); REG(F0W3,64,128,128,128); REG(F0W4,64,64,64,64);
    REG(DW0,256,227,227,256);  REG(DW1,128,256,256,256);  REG(DW2,64,128,128,128);
    REG(DW3,32,64,64,64);      REG(DW4,16,32,32,32);      REG(DWF,3,16,16,32);
    REG(E0W1,128,70,70,96);    REG(E0W2,64,128,128,128);
    REG(E1W1,256,128,128,128); REG(E1W2,128,256,256,256);
    REG(F1W3,128,256,256,256); REG(F1W4,128,128,128,128);
    REG(F1W1,384,192,448,192);   // offs[16]: fc1 gemm1 (folded K=192)
    REG(F1W2,256,384,384,384);   // offs[17]: fc1 gemm2
  }
  packw_all_k<<<CDIV(ptotal,256),256,0,stream>>>(ptab, gwhi, gwlo, ptotal);

  auto OFF = [&](const float* p){ return (int)(p - wcvt); };
  const int HOFF0 = (int)(fold0 - wcvt);
  MCfg cfc0{};
  cfc0.L[0] = { 99,192,4,6, offs[0], OFF(F0S1), HOFF0,     0,1, 0.f};
  cfc0.L[1] = {192,128,6,4, offs[1], OFF(F0S2), OFF(F0H2), 0,1, 0.f};
  cfc0.L[2] = {128, 64,4,2, offs[2], OFF(F0S3), OFF(F0H3), 0,1, 0.f};
  cfc0.L[3] = { 64, 64,2,2, offs[3], 0,         OFF(F0B4), 1,0, 0.f};
  MCfg cdec{};
  cdec.L[0] = {227,256,8,8, offs[4], 0, OFF(DB0), 2,2, 30.f};
  cdec.L[1] = {256,128,8,4, offs[5], 0, OFF(DB1), 1,2, 0.f};
  cdec.L[2] = {128, 64,4,2, offs[6], 0, OFF(DB2), 1,2, 0.f};
  cdec.L[3] = { 64, 32,2,1, offs[7], 0, OFF(DB3), 1,2, 0.f};
  cdec.L[4] = { 32, 16,1,1, offs[8], 0, OFF(DB4), 1,2, 0.f};
  cdec.L[5] = { 16,  3,1,1, offs[9], 0, OFF(DBF), 1,0, 0.f};
  MCfg ce0{};
  ce0.L[0] = { 70,128,3,4, offs[10], OFF(E0S1), OFF(E0H1), 0,1, 0.f};
  ce0.L[1] = {128, 64,4,2, offs[11], 0,         OFF(E0B2), 1,0, 0.f};
  MCfg ce1{};
  ce1.L[0] = {128,256,4,8, offs[12], OFF(E1S1), OFF(E1H1), 0,1, 0.f};
  ce1.L[1] = {256,128,8,4, offs[13], 0,         OFF(E1B2), 1,0, 0.f};
  MCfg cf1t{};
  cf1t.L[0] = {256,128,8,4, offs[14], OFF(F1S3), OFF(F1H3), 0,1, 0.f};
  cf1t.L[1] = {128,128,4,4, offs[15], 0,         OFF(F1B4), 1,0, 0.f};

  const float invN = 1.f/(float)N_PTS;

  featin_k<<<CDIV(N_PTS*35,256),256,0,stream>>>(d_in[1], d_in[2], x_feat, flag);

  // ---- phase 1: emb block 0 — fused gather+MLP (no edge buffer)
  {
    float* eOut = S;               // [79360,64] = 5,079,040
    mlp_edge_k<2><<<CDIV(N_EDGE,64),256,0,stream>>>(
        x_feat, 0, 35, idx0, 0, N_EDGE, ce0, gwhi,gwlo,wcvt, eOut,64);
    kmax_k<<<CDIV(N_PTS*64,256),256,0,stream>>>(eOut, 64, 64, f1b, 0, N_PTS);
  }
  reduce1_k<64><<<256,256,0,stream>>>(f1b, N_PTS, pmax, psum);
  red2fold_k<64><<<1,256,0,stream>>>(pmax, psum, 256, invN,
                                     F0W1,227, 99,163, F0S1,F0H1, fold0, 192);
  // fc0: varying-only concat (99 ch) then ONE fused MLP
  {
    float* h = S;   // [N,99]
    concat2_k<<<CDIV(N_PTS*99,256),256,0,stream>>>(x_feat,0,35, f1b,64, h, 0, N_PTS);
    mlp_fused_k<4,0><<<CDIV(N_PTS,64),256,0,stream>>>(
        h,99,99,N_PTS, cfc0, gwhi,gwlo,wcvt, x_feat+35,227, nullptr, flag);
  }

  // ---- phase 2: dynamic KNN (MFMA)
  norms_k<<<CDIV(N_PTS,256),256,0,stream>>>(x_feat, nrm);
  {
    const int PLANE = NTILE*5*64*8;
    ushort_t* ajhi = (ushort_t*)S;
    ushort_t* ajlo = ajhi + PLANE;
    ushort_t* bihi = ajlo + PLANE;
    ushort_t* bilo = bihi + PLANE;
    packknn_k<<<CDIV(PLANE,256),256,0,stream>>>(x_feat, nrm, ajhi, ajlo, bihi, bilo);
    knn_mfma_k<<<NTILE,256,0,stream>>>(ajhi, ajlo, bihi, bilo, idx1);
  }

  // ---- phase 3: emb block 1 — fused gather+MLP, 2 chunks
  {
    const int P1 = 7936;             // points/chunk -> 39680 edges
    for (int n0 = 0; n0 < N_PTS; n0 += P1) {
      int np = N_PTS - n0; if (np > P1) np = P1;
      int ne = np * KNN_K;
      float* eOut = S;               // [39680,128] = 5,079,040
      mlp_edge_k<2><<<CDIV(ne,64),256,0,stream>>>(
          x_feat, 35, 64, idx1, n0, ne, ce1, gwhi,gwlo,wcvt, eOut,128);
      kmax_k<<<CDIV(np*128,256),256,0,stream>>>(eOut, 128, 128, f1b, n0, np);
    }
  }
  reduce1_k<128><<<256,256,0,stream>>>(f1b, N_PTS, pmax, psum);
  red2fold_k<128><<<1,256,0,stream>>>(pmax, psum, 256, invN,
                                      F1W1,448, 192,320, F1S1,F1H1, fold1, 384);
  // ---- fc1: full-N (no chunking)
  {
    float* h  = S;                   // [N,192]
    float* a1 = S + 3047424;         // [N,384]
    int gx = CDIV(N_PTS,64);         // 248
    concat2_k<<<CDIV(N_PTS*192,256),256,0,stream>>>(x_feat,35,64, f1b,128, h, 0, N_PTS);
    gemm_mfma_k<1><<<dim3(gx,3),256,0,stream>>>(h,192,192,N_PTS, gwhi,gwlo, offs[16],6,
                                                F1S1,fold1, a1,384, 384);
    gemm_mfma_k<1><<<dim3(gx,2),256,0,stream>>>(a1,384,384,N_PTS, gwhi,gwlo, offs[17],12,
                                                F1S2,F1H2, h,256, 256);
    mlp_fused_k<2,0><<<gx,256,0,stream>>>(
        h,256,256,N_PTS, cf1t, gwhi,gwlo,wcvt, x_feat+99,227, nullptr, flag);
  }

  // ---- phase 4: fused SIREN -> logits; softmax gather -> z (round-11 path)
  siren_fused_k<<<CDIV(UP_ROWS,128),256,0,stream>>>(
      d_in[36], whi, UPW0, UPS0, UPH0, UPHR, UPWF, UPBF, logits, flag);
  float* zbuf = S;                 // [M,227]
  softgather_k<<<CDIV(M_PTS,4),256,0,stream>>>(logits, upidx, x_feat, zbuf);

  // ---- phase 5: SIREN decoder: ONE fused MLP (incl. 16->3 head + output)
  mlp_fused_k<6,1><<<CDIV(M_PTS,64),256,0,stream>>>(
      zbuf,227,227,M_PTS, cdec, gwhi,gwlo,wcvt, nullptr,0, d_out, flag);
}

// Round 14
// 1719.747 us; speedup vs baseline: 1.1622x; 1.0342x over previous
//
#include <hip/hip_runtime.h>
#include <hip/hip_bf16.h>
#include <math.h>

#define N_PTS 15872
#define M_PTS 35637
#define KNN_K 5
#define KUP   20
#define UP_ROWS (M_PTS * KUP)   // 712740
#define NTILE (N_PTS/32)        // 496 i/j tiles
#define N_EDGE (N_PTS*KNN_K)    // 79360
#define CDIV(a,b) (((a)+(b)-1)/(b))
#define INV2PI 0.15915494309189535f

typedef __hip_bfloat16 bf16;
typedef unsigned int uint;
typedef unsigned short ushort_t;
__device__ __forceinline__ float b2f(bf16 x){ return __bfloat162float(x); }

// round-to-nearest-even fp32 -> bf16 bit pattern (finite inputs)
__device__ __forceinline__ uint f2bf_bits(float x){
  uint u = __float_as_uint(x);
  return (u + 0x7FFFu + ((u>>16)&1u)) >> 16;
}

// fp32 -> fp16 bits (RNE via hardware cvt)
__device__ __forceinline__ ushort_t f2h_bits(float x){
  union { _Float16 h; ushort_t u; } c; c.h = (_Float16)x; return c.u;
}

// sin with input in REVOLUTIONS (v_sin_f32 semantics); weights/biases are
// pre-scaled by 1/2pi so this is a single VALU op.
__device__ __forceinline__ float sinrev(float x){
#if __has_builtin(__builtin_amdgcn_sinf)
  return __builtin_amdgcn_sinf(x);
#else
  return __sinf(x * 6.283185307179586f);
#endif
}

// monotone float<->uint bijection: unsigned compare == float compare (finite).
// atomicMax on flipped keys == exact float max. Init key 0 < flip(any finite).
__device__ __forceinline__ uint fflip(float f){
  uint u = __float_as_uint(f);
  return (u & 0x80000000u) ? ~u : (u | 0x80000000u);
}
__device__ __forceinline__ float funflip(uint u){
  u = (u & 0x80000000u) ? (u & 0x7FFFFFFFu) : ~u;
  return __uint_as_float(u);
}

typedef __attribute__((ext_vector_type(8))) short bf16x8;
typedef __attribute__((ext_vector_type(8))) _Float16 f16x8;
typedef __attribute__((ext_vector_type(2))) __fp16 fp16x2_t;
typedef __attribute__((ext_vector_type(16))) float f32x16;
union FragAB { bf16x8 v; uint u[4]; };
union FragB  { bf16x8 v; uint4 q; };
union FragH  { f16x8 v; uint4 q; _Float16 h[8]; };
union Acc16  { f32x16 v; float f[16]; };
union H2U    { fp16x2_t h; uint u; };

// ---------------------------------------------------------------------------
__global__ void flag_k(const uint* __restrict__ pos_raw, int* __restrict__ flag){
  if (threadIdx.x == 0 && blockIdx.x == 0)
    flag[0] = (pos_raw[0] == 0x3F800000u) ? 1 : 0;
}

struct CvtTab { const void* src[52]; int start[52]; };
__global__ __launch_bounds__(256) void cvt_all_k(CvtTab tab, float* __restrict__ dst,
                                                 const int* __restrict__ flag, int total){
  int i = blockIdx.x*256 + threadIdx.x;
  if (i >= total) return;
  int s = 0;
#pragma unroll 1
  for (int k = 1; k < 52; k++) if (tab.start[k] <= i) s = k;
  int off = i - tab.start[s];
  float v = flag[0] ? b2f(((const bf16*)tab.src[s])[off]) : ((const float*)tab.src[s])[off];
  dst[i] = v;
}

// pack SIREN 128x128 weights into frag-major fp16 plane; per-layer output
// scale AND 1/2pi folded in (epilogue uses raw v_sin on revolutions).
// sigma-fold: store W[n][sigma(k)] at physical slot k so the consuming
// lane's next-layer B-frag assembles from its OWN registers.
__global__ void packfrag16_k(const float* __restrict__ w, const float* __restrict__ sr,
                             ushort_t* __restrict__ out, int n){
  int i = blockIdx.x*256 + threadIdx.x;
  if (i >= n) return;
  int j = i & 7;
  int lam = (i >> 3) & 63;
  int fg = i >> 9;
  int t = fg & 3, ks = (fg >> 2) & 1, Q = (fg >> 3) & 3, l = fg >> 5;
  int nn = t*32 + (lam & 31);
  int kk = Q*32 + ks*16 + ((j>>2)<<3) + ((lam>>5)<<2) + (j&3);   // sigma-fold
  float x = w[l*16384 + nn*128 + kk] * sr[l*128 + nn] * INV2PI;
  out[i] = f2h_bits(x);
}

// batched frag-major split-bf16 pack for all 18 weight matrices in ONE launch.
struct PackTab { const float* src[18]; int N[18], K[18], ldk[18], Kpad[18], start[18]; };
__global__ __launch_bounds__(256) void packw_all_k(PackTab t, ushort_t* __restrict__ whi,
                                                   ushort_t* __restrict__ wlo, int total){
  int i = blockIdx.x*256 + threadIdx.x;
  if (i >= total) return;
  int s = 0;
#pragma unroll 1
  for (int q = 1; q < 18; q++) if (t.start[q] <= i) s = q;
  int ii = i - t.start[s];
  int j = ii & 7;
  int lane = (ii >> 3) & 63;
  int fr = ii >> 9;
  int nq = t.Kpad[s] >> 5;
  int ks = fr & 1;
  int q  = (fr >> 1) % nq;
  int nt = (fr >> 1) / nq;
  int n = nt*32 + (lane & 31);
  int k = q*32 + ks*16 + (lane >> 5)*8 + j;
  float x = (n < t.N[s] && k < t.K[s]) ? t.src[s][(size_t)n*t.ldk[s] + k] : 0.f;
  uint hb = f2bf_bits(x);
  uint lb = f2bf_bits(x - __uint_as_float(hb << 16));
  whi[i] = (ushort_t)hb;
  wlo[i] = (ushort_t)lb;
}

// pack KNN features into frag-major split-bf16 planes with norm augmentation.
__global__ void packknn_k(const float* __restrict__ xf, const float* __restrict__ nr,
                          ushort_t* __restrict__ ahi, ushort_t* __restrict__ alo,
                          ushort_t* __restrict__ bhi, ushort_t* __restrict__ blo){
  int i = blockIdx.x*256 + threadIdx.x;
  if (i >= NTILE*5*64*8) return;
  int e = i & 7;
  int lane = (i >> 3) & 63;
  int rest = i >> 9;
  int kc = rest % 5, jt = rest / 5;
  int n = jt*32 + (lane & 31);
  int k = kc*16 + (lane >> 5)*8 + e;
  float f = (k < 64) ? xf[(size_t)n*227 + 35 + k] : 0.f;
  float av, bv;
  if (k < 64)      { av = 2.f*f;   bv = f; }
  else if (k == 64){ av = nr[n];   bv = -1.f; }
  else if (k == 65){ av = 1.f;     bv = -nr[n]; }
  else             { av = 0.f;     bv = 0.f; }
  uint ah = f2bf_bits(av); uint al = f2bf_bits(av - __uint_as_float(ah<<16));
  uint bh = f2bf_bits(bv); uint bl = f2bf_bits(bv - __uint_as_float(bh<<16));
  ahi[i] = (ushort_t)ah; alo[i] = (ushort_t)al;
  bhi[i] = (ushort_t)bh; blo[i] = (ushort_t)bl;
}

__global__ void fillmark_k(bf16* __restrict__ out, int n){
  int i = blockIdx.x*256 + threadIdx.x;
  if (i < n) out[i] = __float2bfloat16(12345.0f);
}

// ---------------------------------------------------------------------------
// Single-layer split-bf16 MFMA GEMM (validated round 8): 128-col panels,
// acc[2], K-chunked 32 KB slab. Used for fc1's 192->384 and 384->256.
// ---------------------------------------------------------------------------
template<int ACT>
__global__ __launch_bounds__(256) void gemm_mfma_k(
    const float* __restrict__ A, int lda, int K, int M,
    const ushort_t* __restrict__ wh, const ushort_t* __restrict__ wl,
    int woff, int KqTot,
    const float* __restrict__ scale, const float* __restrict__ shift,
    float* __restrict__ C, int ldc, int N)
{
  __shared__ __align__(16) uint slab[64*128];   // 32768 B
  const int tid = threadIdx.x;
  const int lane = tid & 63;
  const int wv = tid >> 6;
  const int np = lane & 31;
  const int hb2 = lane >> 5;
  const int rhalf = wv & 1, thalf = wv >> 1;
  const int rb = blockIdx.x * 64;
  const int tbase = blockIdx.y * 4;
  const int row_l = rhalf*32 + np;
  int NtLoc = (N >> 5) - tbase; if (NtLoc > 4) NtLoc = 4;

  Acc16 acc[2];
#pragma unroll
  for (int u=0;u<2;u++)
#pragma unroll
    for (int i=0;i<16;i++) acc[u].f[i] = 0.f;

#pragma unroll 1
  for (int k0 = 0; k0 < K; k0 += 128) {
    for (int e = tid; e < 64*32; e += 256) {
      int r = e >> 5, g = e & 31;
      int gr = rb + r;
      uint p[4];
#pragma unroll
      for (int u=0;u<4;u++){
        int k = k0 + g*4 + u;
        float f = (gr < M && k < K) ? A[(size_t)gr*lda + k] : 0.f;
        uint hb = f2bf_bits(f);
        uint lb = f2bf_bits(f - __uint_as_float(hb<<16));
        p[u] = (hb<<16) | lb;
      }
      *(uint4*)&slab[r*128 + (((g ^ r) & 31)<<2)] = make_uint4(p[0],p[1],p[2],p[3]);
    }
    __syncthreads();
    int qb = k0 >> 5;
    int KqLoc = KqTot - qb; if (KqLoc > 4) KqLoc = 4;
#pragma unroll 1
    for (int q = 0; q < KqLoc; q++){
#pragma unroll
      for (int ks = 0; ks < 2; ks++){
        int g0 = q*8 + ks*4 + hb2*2;
        uint4 a0 = *(const uint4*)&slab[row_l*128 + ((((g0  ) ^ row_l) & 31)<<2)];
        uint4 a1 = *(const uint4*)&slab[row_l*128 + ((((g0+1) ^ row_l) & 31)<<2)];
        uint au[8] = {a0.x,a0.y,a0.z,a0.w,a1.x,a1.y,a1.z,a1.w};
        FragAB ah, al;
#pragma unroll
        for (int p=0;p<4;p++){
          ah.u[p] = (au[2*p]>>16)     | (au[2*p+1] & 0xFFFF0000u);
          al.u[p] = (au[2*p]&0xFFFFu) | (au[2*p+1]<<16);
        }
#pragma unroll
        for (int u=0;u<2;u++){
          int t = thalf + u*2;
          if (t < NtLoc){
            size_t fb = (size_t)woff + ((size_t)(((tbase+t)*KqTot + qb + q)*2 + ks))*512 + (size_t)lane*8;
            FragB bh, bl;
            bh.q = *(const uint4*)(wh + fb);
            bl.q = *(const uint4*)(wl + fb);
            acc[u].v = __builtin_amdgcn_mfma_f32_32x32x16_bf16(ah.v, bh.v, acc[u].v, 0,0,0);
            acc[u].v = __builtin_amdgcn_mfma_f32_32x32x16_bf16(al.v, bh.v, acc[u].v, 0,0,0);
            acc[u].v = __builtin_amdgcn_mfma_f32_32x32x16_bf16(ah.v, bl.v, acc[u].v, 0,0,0);
          }
        }
      }
    }
    __syncthreads();
  }

#pragma unroll
  for (int u=0;u<2;u++){
    int t = thalf + u*2;
    if (t < NtLoc){
      int col = (tbase+t)*32 + np;
      float scv = scale[col], shv = shift[col];
#pragma unroll
      for (int reg=0;reg<16;reg++){
        int r32 = (reg&3) + 8*(reg>>2) + 4*hb2;
        int gr = rb + rhalf*32 + r32;
        if (gr < M){
          float v = acc[u].f[reg]*scv + shv;
          if (ACT==1) v = v > 0.f ? v : 0.2f*v;
          C[(size_t)gr*ldc + col] = v;
        }
      }
    }
  }
}

// ---------------------------------------------------------------------------
// Generic fused per-row MLP (validated round 9): up to 6 layers, dims <= 256.
// ---------------------------------------------------------------------------
struct MLayer { int K, N, Kq, Nt, woff, soff, hoff, epi, act; float gmul; };
struct MCfg { MLayer L[6]; };

template<int NL, int OUTMODE>
__global__ __launch_bounds__(256) void mlp_fused_k(
    const float* __restrict__ A0, int lda0, int K0, int M,
    MCfg cfg,
    const ushort_t* __restrict__ wh, const ushort_t* __restrict__ wl,
    const float* __restrict__ wc,
    float* __restrict__ Cout, int ldc,
    void* __restrict__ oflg, const int* __restrict__ flag)
{
  __shared__ __align__(16) uint slab[64*256];   // 65536 B
  const int tid = threadIdx.x;
  const int lane = tid & 63;
  const int wv = tid >> 6;
  const int np = lane & 31;
  const int hb2 = lane >> 5;
  const int rhalf = wv & 1, thalf = wv >> 1;
  const int rb = blockIdx.x * 64;
  const int row_l = rhalf*32 + np;

  for (int e = tid; e < 64*64; e += 256) {
    int r = e >> 6, g = e & 63;
    int gr = rb + r;
    uint p[4];
#pragma unroll
    for (int u=0;u<4;u++){
      int k = g*4+u;
      float f = (gr < M && k < K0) ? A0[(size_t)gr*lda0 + k] : 0.f;
      uint hb = f2bf_bits(f);
      uint lb = f2bf_bits(f - __uint_as_float(hb<<16));
      p[u] = (hb<<16) | lb;
    }
    *(uint4*)&slab[r*256 + (((g ^ r) & 63)<<2)] = make_uint4(p[0],p[1],p[2],p[3]);
  }
  __syncthreads();

#pragma unroll 1
  for (int l = 0; l < NL; l++){
    const int N = cfg.L[l].N, Kq = cfg.L[l].Kq, Nt = cfg.L[l].Nt;
    const int woff = cfg.L[l].woff, soff = cfg.L[l].soff, hoff = cfg.L[l].hoff;
    const int epi = cfg.L[l].epi, actf = cfg.L[l].act;
    const float gmul = cfg.L[l].gmul;
    Acc16 acc[4];
#pragma unroll
    for (int u=0;u<4;u++)
#pragma unroll
      for (int i=0;i<16;i++) acc[u].f[i] = 0.f;

#pragma unroll 1
    for (int q = 0; q < Kq; q++){
#pragma unroll
      for (int ks = 0; ks < 2; ks++){
        int g0 = (q*32 + ks*16 + hb2*8) >> 2;
        uint4 a0 = *(const uint4*)&slab[row_l*256 + ((((g0  ) ^ row_l) & 63)<<2)];
        uint4 a1 = *(const uint4*)&slab[row_l*256 + ((((g0+1) ^ row_l) & 63)<<2)];
        uint au[8] = {a0.x,a0.y,a0.z,a0.w,a1.x,a1.y,a1.z,a1.w};
        FragAB ah, al;
#pragma unroll
        for (int p=0;p<4;p++){
          ah.u[p] = (au[2*p]>>16)     | (au[2*p+1] & 0xFFFF0000u);
          al.u[p] = (au[2*p]&0xFFFFu) | (au[2*p+1]<<16);
        }
#pragma unroll
        for (int u=0;u<4;u++){
          int t = thalf + u*2;
          if (t < Nt){
            size_t fb = (size_t)woff + ((size_t)((t*Kq + q)*2 + ks))*512 + (size_t)lane*8;
            FragB bh, bl;
            bh.q = *(const uint4*)(wh + fb);
            bl.q = *(const uint4*)(wl + fb);
            acc[u].v = __builtin_amdgcn_mfma_f32_32x32x16_bf16(ah.v, bh.v, acc[u].v, 0,0,0);
            acc[u].v = __builtin_amdgcn_mfma_f32_32x32x16_bf16(al.v, bh.v, acc[u].v, 0,0,0);
            acc[u].v = __builtin_amdgcn_mfma_f32_32x32x16_bf16(ah.v, bl.v, acc[u].v, 0,0,0);
          }
        }
      }
    }
    __syncthreads();
#pragma unroll
    for (int u=0;u<4;u++){
      int t = thalf + u*2;
      if (t < Nt){
        int col = t*32 + np;
        if (col < N){
          float scv = (epi==0) ? wc[soff+col] : 0.f;
          float shv = wc[hoff+col];
#pragma unroll
          for (int reg=0;reg<16;reg++){
            int r32 = (reg&3) + 8*(reg>>2) + 4*hb2;
            float v = acc[u].f[reg];
            if (epi==0)      v = v*scv + shv;
            else if (epi==1) v = v + shv;
            else             v = (v + shv)*gmul;
            if (actf==1)      v = v > 0.f ? v : 0.2f*v;
            else if (actf==2) v = __sinf(v);
            if (l == NL-1){
              int gr = rb + rhalf*32 + r32;
              if (gr < M){
                if (OUTMODE==0) Cout[(size_t)gr*ldc + col] = v;
                else {
                  if (!(fabsf(v) < 1e30f)) v = 777.0f;  // canary
                  size_t oi = (size_t)gr*3 + col;
                  if (flag[0]) ((bf16*)oflg)[oi] = __float2bfloat16(v);
                  else         ((float*)oflg)[oi] = v;
                }
              }
            } else {
              int r = rhalf*32 + r32;
              uint hb = f2bf_bits(v);
              uint lb = f2bf_bits(v - __uint_as_float(hb<<16));
              slab[r*256 + ((((col>>2) ^ r) & 63)<<2) + (col&3)] = (hb<<16) | lb;
            }
          }
        }
      }
    }
    __syncthreads();
  }
}

// ---------------------------------------------------------------------------
// Edge-conv MLP with FUSED GATHER staging (round 13) + FUSED KMAX epilogue
// (round 14): final-layer values go through ordered-uint atomicMax directly
// into f1b[point*Cch+col] (flipped encoding; exact float max). No edge output
// buffer, no separate kmax kernel. f1b must be pre-memset to 0.
// ---------------------------------------------------------------------------
template<int NL>
__global__ __launch_bounds__(256) void mlp_edge_k(
    const float* __restrict__ xf, int coff, int CIN,
    const int* __restrict__ idx, int n0, int M /*edges*/,
    MCfg cfg,
    const ushort_t* __restrict__ wh, const ushort_t* __restrict__ wl,
    const float* __restrict__ wc,
    uint* __restrict__ f1out, int Cch)
{
  __shared__ __align__(16) uint slab[64*256];   // 65536 B
  const int tid = threadIdx.x;
  const int lane = tid & 63;
  const int wv = tid >> 6;
  const int np = lane & 31;
  const int hb2 = lane >> 5;
  const int rhalf = wv & 1, thalf = wv >> 1;
  const int rb = blockIdx.x * 64;
  const int row_l = rhalf*32 + np;
  const int W2 = 2*CIN;

  for (int e = tid; e < 64*64; e += 256) {
    int r = e >> 6, g = e & 63;
    int ek = rb + r;
    int n = 0, j = 0;
    bool ok = (ek < M);
    if (ok){
      n = n0 + ek/KNN_K;
      j = idx[n*KNN_K + ek%KNN_K];
    }
    uint p[4];
#pragma unroll
    for (int u=0;u<4;u++){
      int k = g*4+u;
      float f = 0.f;
      if (ok && k < W2){
        f = (k < CIN) ? xf[(size_t)j*227 + coff + k] - xf[(size_t)n*227 + coff + k]
                      : xf[(size_t)n*227 + coff + (k-CIN)];
      }
      uint hb = f2bf_bits(f);
      uint lb = f2bf_bits(f - __uint_as_float(hb<<16));
      p[u] = (hb<<16) | lb;
    }
    *(uint4*)&slab[r*256 + (((g ^ r) & 63)<<2)] = make_uint4(p[0],p[1],p[2],p[3]);
  }
  __syncthreads();

#pragma unroll 1
  for (int l = 0; l < NL; l++){
    const int N = cfg.L[l].N, Kq = cfg.L[l].Kq, Nt = cfg.L[l].Nt;
    const int woff = cfg.L[l].woff, soff = cfg.L[l].soff, hoff = cfg.L[l].hoff;
    const int epi = cfg.L[l].epi, actf = cfg.L[l].act;
    Acc16 acc[4];
#pragma unroll
    for (int u=0;u<4;u++)
#pragma unroll
      for (int i=0;i<16;i++) acc[u].f[i] = 0.f;

#pragma unroll 1
    for (int q = 0; q < Kq; q++){
#pragma unroll
      for (int ks = 0; ks < 2; ks++){
        int g0 = (q*32 + ks*16 + hb2*8) >> 2;
        uint4 a0 = *(const uint4*)&slab[row_l*256 + ((((g0  ) ^ row_l) & 63)<<2)];
        uint4 a1 = *(const uint4*)&slab[row_l*256 + ((((g0+1) ^ row_l) & 63)<<2)];
        uint au[8] = {a0.x,a0.y,a0.z,a0.w,a1.x,a1.y,a1.z,a1.w};
        FragAB ah, al;
#pragma unroll
        for (int p=0;p<4;p++){
          ah.u[p] = (au[2*p]>>16)     | (au[2*p+1] & 0xFFFF0000u);
          al.u[p] = (au[2*p]&0xFFFFu) | (au[2*p+1]<<16);
        }
#pragma unroll
        for (int u=0;u<4;u++){
          int t = thalf + u*2;
          if (t < Nt){
            size_t fb = (size_t)woff + ((size_t)((t*Kq + q)*2 + ks))*512 + (size_t)lane*8;
            FragB bh, bl;
            bh.q = *(const uint4*)(wh + fb);
            bl.q = *(const uint4*)(wl + fb);
            acc[u].v = __builtin_amdgcn_mfma_f32_32x32x16_bf16(ah.v, bh.v, acc[u].v, 0,0,0);
            acc[u].v = __builtin_amdgcn_mfma_f32_32x32x16_bf16(al.v, bh.v, acc[u].v, 0,0,0);
            acc[u].v = __builtin_amdgcn_mfma_f32_32x32x16_bf16(ah.v, bl.v, acc[u].v, 0,0,0);
          }
        }
      }
    }
    __syncthreads();
#pragma unroll
    for (int u=0;u<4;u++){
      int t = thalf + u*2;
      if (t < Nt){
        int col = t*32 + np;
        if (col < N){
          float scv = (epi==0) ? wc[soff+col] : 0.f;
          float shv = wc[hoff+col];
#pragma unroll
          for (int reg=0;reg<16;reg++){
            int r32 = (reg&3) + 8*(reg>>2) + 4*hb2;
            float v = acc[u].f[reg];
            if (epi==0)      v = v*scv + shv;
            else             v = v + shv;
            if (actf==1)     v = v > 0.f ? v : 0.2f*v;
            if (l == NL-1){
              int gr = rb + rhalf*32 + r32;
              if (gr < M){
                int pt = n0 + gr/KNN_K;
                atomicMax(&f1out[(size_t)pt*Cch + col], fflip(v));
              }
            } else {
              int r = rhalf*32 + r32;
              uint hb = f2bf_bits(v);
              uint lb = f2bf_bits(v - __uint_as_float(hb<<16));
              slab[r*256 + ((((col>>2) ^ r) & 63)<<2) + (col&3)] = (hb<<16) | lb;
            }
          }
        }
      }
    }
    __syncthreads();
  }
}

// ---------------------------------------------------------------------------
// MFMA KNN (validated round 7).
// ---------------------------------------------------------------------------
#define INS5(tv, tj, v, j) \
  if ((v) > tv[4]){ tv[4]=(v); tj[4]=(j); \
    _Pragma("unroll") \
    for (int q=4;q>0;q--) \
      if (tv[q] > tv[q-1]){ float tf=tv[q-1]; tv[q-1]=tv[q]; tv[q]=tf; \
                            int ti=tj[q-1]; tj[q-1]=tj[q]; tj[q]=ti; } }

__global__ __launch_bounds__(256) void knn_mfma_k(
    const ushort_t* __restrict__ ahi, const ushort_t* __restrict__ alo,
    const ushort_t* __restrict__ bhi, const ushort_t* __restrict__ blo,
    int* __restrict__ out)
{
  __shared__ float mv[4][32][5];
  __shared__ int   mjj[4][32][5];
  const int tid = threadIdx.x;
  const int lane = tid & 63;
  const int wv = tid >> 6;
  const int np = lane & 31;
  const int hb2 = lane >> 5;
  const int it = blockIdx.x;
  const int ig = it*32 + np;

  FragB vh[5], vl[5];
  {
    size_t bb = (size_t)(it*5)*512 + (size_t)lane*8;
#pragma unroll
    for (int kc=0;kc<5;kc++){
      vh[kc].q = *(const uint4*)(bhi + bb + kc*512);
      vl[kc].q = *(const uint4*)(blo + bb + kc*512);
    }
  }

  float tv[5] = {-1e30f,-1e30f,-1e30f,-1e30f,-1e30f};
  int   tj[5] = {0,0,0,0,0};

  FragB uh[5], ul[5], nh[5], nl[5];
  {
    size_t ab = (size_t)(wv*5)*512 + (size_t)lane*8;
#pragma unroll
    for (int kc=0;kc<5;kc++){
      uh[kc].q = *(const uint4*)(ahi + ab + kc*512);
      ul[kc].q = *(const uint4*)(alo + ab + kc*512);
    }
  }

#pragma unroll 1
  for (int t = 0; t < NTILE/4; t++){
    int jt = wv + t*4;
    if (t+1 < NTILE/4){
      size_t an = (size_t)((jt+4)*5)*512 + (size_t)lane*8;
#pragma unroll
      for (int kc=0;kc<5;kc++){
        nh[kc].q = *(const uint4*)(ahi + an + kc*512);
        nl[kc].q = *(const uint4*)(alo + an + kc*512);
      }
    }
    Acc16 acc;
#pragma unroll
    for (int q=0;q<16;q++) acc.f[q] = 0.f;
#pragma unroll
    for (int kc=0;kc<5;kc++){
      acc.v = __builtin_amdgcn_mfma_f32_32x32x16_bf16(uh[kc].v, vh[kc].v, acc.v, 0,0,0);
      acc.v = __builtin_amdgcn_mfma_f32_32x32x16_bf16(ul[kc].v, vh[kc].v, acc.v, 0,0,0);
      acc.v = __builtin_amdgcn_mfma_f32_32x32x16_bf16(uh[kc].v, vl[kc].v, acc.v, 0,0,0);
    }
    int jb = jt*32 + 4*hb2;
#pragma unroll
    for (int reg=0;reg<16;reg++){
      int j = jb + (reg&3) + 8*(reg>>2);
      float v = acc.f[reg];
      if (j != ig) { INS5(tv, tj, v, j); }
    }
    if (t+1 < NTILE/4){
#pragma unroll
      for (int kc=0;kc<5;kc++){ uh[kc] = nh[kc]; ul[kc] = nl[kc]; }
    }
  }

#pragma unroll
  for (int s=0;s<5;s++){
    float ov = __shfl_xor(tv[s], 32, 64);
    int   oj = __shfl_xor(tj[s], 32, 64);
    INS5(tv, tj, ov, oj);
  }
  if (hb2 == 0){
#pragma unroll
    for (int s=0;s<5;s++){ mv[wv][np][s] = tv[s]; mjj[wv][np][s] = tj[s]; }
  }
  __syncthreads();
  if (tid < 32){
    float bv[5]; int bj[5];
#pragma unroll
    for (int s=0;s<5;s++){ bv[s] = mv[0][tid][s]; bj[s] = mjj[0][tid][s]; }
#pragma unroll
    for (int w=1;w<4;w++)
#pragma unroll
      for (int s=0;s<5;s++){
        float v = mv[w][tid][s]; int j = mjj[w][tid][s];
        INS5(bv, bj, v, j);
      }
    int gi = it*32 + tid;
#pragma unroll
    for (int s=0;s<5;s++) out[gi*KNN_K + s] = bj[s];
  }
}

// ---------------------------------------------------------------------------
// Fused 8-layer SIREN + head (v9, validated round 11): register-resident acts
// + sigma-fold + 1/2pi-folded weights -> raw v_sin. One barrier.
// ---------------------------------------------------------------------------
__global__ __launch_bounds__(256) void siren_fused_k(
    const void* __restrict__ upin,
    const ushort_t* __restrict__ wf16,
    const float* __restrict__ W0c, const float* __restrict__ S0c, const float* __restrict__ H0c,
    const float* __restrict__ HRc,
    const float* __restrict__ WFc, const float* __restrict__ BFc,
    float* __restrict__ logits, const int* __restrict__ flag)
{
  __shared__ float intile[4*32*8];                   // 4096 B
  __shared__ __align__(16) float w0s[128*8];         // 4096 B (scale*inv2pi, bias slot 7)
  __shared__ __align__(16) float hrs[7*128];         // 3584 B biases * inv2pi
  __shared__ __align__(16) float wfs[128];
  __shared__ float bfs[1];

  const int tid  = threadIdx.x;
  const int lane = tid & 63;
  const int wv   = tid >> 6;
  const int np   = lane & 31;
  const int hb2  = lane >> 5;
  const int rowbase = blockIdx.x * 128 + wv * 32;
  const int isbf = flag[0];
  float* intw = intile + wv*32*8;

  for (int e = tid; e < 128*7; e += 256){
    int c = e/7, k = e%7;
    w0s[c*8+k] = W0c[e]*S0c[c]*INV2PI;
  }
  if (tid < 128) w0s[tid*8+7] = H0c[tid]*INV2PI;
  for (int e = tid; e < 7*128; e += 256) hrs[e] = HRc[e]*INV2PI;
  if (tid < 128) wfs[tid] = WFc[tid];
  if (tid == 0) bfs[0] = BFc[0];
  for (int e = lane; e < 32*7; e += 64) {
    int r = e/7, k = e%7;
    int gr = rowbase + r;
    float v = 0.f;
    if (gr < UP_ROWS)
      v = isbf ? b2f(((const bf16*)upin)[(size_t)gr*7+k]) : ((const float*)upin)[(size_t)gr*7+k];
    intw[r*8+k] = v;
  }
  __syncthreads();   // staged tables ready; ONLY barrier in the kernel

  uint st0[16], st1[16];   // per group: [j0,j1] and [j2,j3] packed fp16
  {
    float xin[7];
#pragma unroll
    for (int k=0;k<7;k++) xin[k] = intw[np*8+k];
#pragma unroll
    for (int g = 0; g < 16; g++){
      float xs[4];
#pragma unroll
      for (int j = 0; j < 4; j++){
        int c = g*8 + hb2*4 + j;
        const float4 wa = *(const float4*)&w0s[c*8];
        const float4 wb = *(const float4*)&w0s[c*8+4];
        float a = wb.w;                     // bias (pre-scaled)
        a += xin[0]*wa.x; a += xin[1]*wa.y; a += xin[2]*wa.z; a += xin[3]*wa.w;
        a += xin[4]*wb.x; a += xin[5]*wb.y; a += xin[6]*wb.z;
        xs[j] = sinrev(a);
      }
      H2U u0,u1;
      u0.h = __builtin_amdgcn_cvt_pkrtz(xs[0],xs[1]);
      u1.h = __builtin_amdgcn_cvt_pkrtz(xs[2],xs[3]);
      st0[g] = u0.u; st1[g] = u1.u;
    }
  }

  FragH fr[8];
#pragma unroll
  for (int m = 0; m < 8; m++)
    fr[m].q = make_uint4(st0[2*m], st1[2*m], st0[2*m+1], st1[2*m+1]);

  uint nst0[16], nst1[16];
#pragma unroll 1
  for (int l = 0; l < 7; l++) {
#pragma unroll
    for (int tp = 0; tp < 2; tp++){
      Acc16 acc0, acc1;
#pragma unroll
      for (int i=0;i<16;i++){ acc0.f[i] = 0.f; acc1.f[i] = 0.f; }
#pragma unroll
      for (int m = 0; m < 8; m++){
        int fb = (((l*8 + m)*4 + tp*2) << 9) + lane*8;
        FragH bh0, bh1;
        bh0.q = *(const uint4*)(wf16 + fb);
        bh1.q = *(const uint4*)(wf16 + fb + 512);
        acc0.v = __builtin_amdgcn_mfma_f32_32x32x16_f16(bh0.v, fr[m].v, acc0.v, 0,0,0);
        acc1.v = __builtin_amdgcn_mfma_f32_32x32x16_f16(bh1.v, fr[m].v, acc1.v, 0,0,0);
      }
#pragma unroll
      for (int rg = 0; rg < 4; rg++){
        int g0 = (tp*2+0)*4 + rg;
        const float4 b0v = *(const float4*)&hrs[l*128 + g0*8 + hb2*4];
        float x0 = sinrev(acc0.f[rg*4+0] + b0v.x);
        float x1 = sinrev(acc0.f[rg*4+1] + b0v.y);
        float x2 = sinrev(acc0.f[rg*4+2] + b0v.z);
        float x3 = sinrev(acc0.f[rg*4+3] + b0v.w);
        H2U u0,u1;
        u0.h = __builtin_amdgcn_cvt_pkrtz(x0,x1);
        u1.h = __builtin_amdgcn_cvt_pkrtz(x2,x3);
        nst0[g0] = u0.u; nst1[g0] = u1.u;

        int g1 = (tp*2+1)*4 + rg;
        const float4 b1v = *(const float4*)&hrs[l*128 + g1*8 + hb2*4];
        float y0 = sinrev(acc1.f[rg*4+0] + b1v.x);
        float y1 = sinrev(acc1.f[rg*4+1] + b1v.y);
        float y2 = sinrev(acc1.f[rg*4+2] + b1v.z);
        float y3 = sinrev(acc1.f[rg*4+3] + b1v.w);
        H2U v0,v1;
        v0.h = __builtin_amdgcn_cvt_pkrtz(y0,y1);
        v1.h = __builtin_amdgcn_cvt_pkrtz(y2,y3);
        nst0[g1] = v0.u; nst1[g1] = v1.u;
      }
    }
    if (l < 6){
#pragma unroll
      for (int m = 0; m < 8; m++)
        fr[m].q = make_uint4(nst0[2*m], nst1[2*m], nst0[2*m+1], nst1[2*m+1]);
    }
  }

  {
    float a = 0.f;
#pragma unroll
    for (int g = 0; g < 16; g++){
      const float4 w4 = *(const float4*)&wfs[g*8 + hb2*4];
      H2U u0,u1; u0.u = nst0[g]; u1.u = nst1[g];
      a += (float)u0.h.x*w4.x + (float)u0.h.y*w4.y
         + (float)u1.h.x*w4.z + (float)u1.h.y*w4.w;
    }
    a += __shfl_xor(a, 32, 64);
    int gr = rowbase + np;
    if (hb2 == 0 && gr < UP_ROWS) logits[gr] = a + bfs[0];
  }
}

// ---------------------------------------------------------------------------
__global__ void featin_k(const void* __restrict__ ldx, const void* __restrict__ pos,
                         float* __restrict__ xf, const int* __restrict__ flag){
  int i = blockIdx.x*256 + threadIdx.x;
  if (i >= N_PTS*35) return;
  int n = i / 35, c = i % 35;
  float v;
  if (flag[0]) {
    v = (c < 3) ? b2f(((const bf16*)ldx)[n*3+c]) : b2f(((const bf16*)pos)[n*32 + (c-3)]);
  } else {
    v = (c < 3) ? ((const float*)ldx)[n*3+c] : ((const float*)pos)[n*32 + (c-3)];
  }
  xf[(size_t)n*227 + c] = v;
}

// reduce over f1b stored in FLIPPED ordered-uint encoding (round 14)
template<int C>
__global__ __launch_bounds__(256) void reduce1_k(const uint* __restrict__ X, int n,
                                                 float* __restrict__ pmax, float* __restrict__ psum){
  const int tid = threadIdx.x;
  const int c = tid % C;
  const int r0 = tid / C;
  const int TPR = 256 / C;
  float vmax = -1e30f, vsum = 0.f;
  for (int row = blockIdx.x * TPR + r0; row < n; row += gridDim.x * TPR) {
    float v = funflip(X[(size_t)row * C + c]);
    vmax = fmaxf(vmax, v); vsum += v;
  }
  __shared__ float smax[256], ssum[256];
  smax[tid]=vmax; ssum[tid]=vsum;
  __syncthreads();
  if (tid < C) {
    for (int q=1;q<TPR;q++){ vmax=fmaxf(vmax, smax[q*C+c]); vsum += ssum[q*C+c]; }
    pmax[blockIdx.x*C + c] = vmax; psum[blockIdx.x*C + c] = vsum;
  }
}

// merged reduce2 + foldshift
template<int C>
__global__ __launch_bounds__(256) void red2fold_k(
    const float* __restrict__ pmax, const float* __restrict__ psum,
    int nblk, float invn,
    const float* __restrict__ W, int ldw, int off1, int off2,
    const float* __restrict__ scale, const float* __restrict__ shift,
    float* __restrict__ out, int N)
{
  __shared__ float smax[C], ssum[C];
  int tid = threadIdx.x;
  if (tid < C){
    float vmax=-1e30f, vsum=0.f;
    for (int b=0;b<nblk;b++){ vmax=fmaxf(vmax,pmax[b*C+tid]); vsum+=psum[b*C+tid]; }
    smax[tid]=vmax; ssum[tid]=vsum*invn;
  }
  __syncthreads();
  for (int n = tid; n < N; n += 256){
    const float* wr = W + (size_t)n*ldw;
    float s = 0.f;
    for (int j=0;j<C;j++) s += wr[off1+j]*smax[j];
    for (int j=0;j<C;j++) s += wr[off2+j]*ssum[j];
    out[n] = s*scale[n] + shift[n];
  }
}

// varying-channels-only concat; f1 is in FLIPPED encoding (round 14)
__global__ void concat2_k(const float* __restrict__ xf, int coff, int CF,
                          const uint* __restrict__ f1, int C,
                          float* __restrict__ h, int n0, int np){
  int W = CF + C;
  int i = blockIdx.x*256 + threadIdx.x;
  if (i >= np*W) return;
  int nl = i / W, c = i % W;
  int n = n0 + nl;
  float v = (c < CF) ? xf[(size_t)n*227 + coff + c]
                     : funflip(f1[(size_t)n*C + (c-CF)]);
  h[(size_t)nl*W + c] = v;
}

__global__ void norms_k(const float* __restrict__ xf, float* __restrict__ nr){
  int n = blockIdx.x*256 + threadIdx.x;
  if (n >= N_PTS) return;
  const float* p = xf + (size_t)n*227 + 35;
  float s = 0.f;
  for (int d=0;d<64;d++) s += p[d]*p[d];
  nr[n] = s;
}

// 4 points per 256-thread block (one per wave) — validated round 11.
__global__ __launch_bounds__(256) void softgather_k(const float* __restrict__ logits,
                                                    const int* __restrict__ up_idx,
                                                    const float* __restrict__ xf,
                                                    float* __restrict__ z){
  __shared__ float lw[4][KUP]; __shared__ int li[4][KUP];
  int sub = threadIdx.x >> 6;
  int tid = threadIdx.x & 63;
  int m = blockIdx.x*4 + sub;
  bool ok = (m < M_PTS);
  if (ok && tid < KUP){
    lw[sub][tid] = logits[(size_t)m*KUP + tid];
    li[sub][tid] = up_idx[(size_t)m*KUP + tid];
  }
  __syncthreads();
  if (ok){
    float mx = -1e30f;
    for (int k=0;k<KUP;k++) mx = fmaxf(mx, lw[sub][k]);
    float w[KUP]; float s = 0.f;
    for (int k=0;k<KUP;k++){ w[k] = expf(lw[sub][k]-mx); s += w[k]; }
    float inv = 1.f/s;
    for (int c = tid; c < 227; c += 64){
      float acc = 0.f;
      for (int k=0;k<KUP;k++) acc += w[k] * xf[(size_t)li[sub][k]*227 + c];
      z[(size_t)m*227 + c] = acc*inv;
    }
  }
}

// ---------------------------------------------------------------------------
extern "C" void kernel_launch(void* const* d_in, const int* in_sizes, int n_in,
                              void* d_out, int out_size, void* d_ws, size_t ws_size,
                              hipStream_t stream) {
  const int *idx0  = (const int*)d_in[3];
  const int *upidx = (const int*)d_in[37];

  // ---- workspace layout (floats) ----
  float* ws = (float*)d_ws;
  float* x_feat = ws;                     // [N,227]
  float* f1b    = ws + 3602944;           // [N,128]  (flipped-uint during edge phases)
  float* pmax   = ws + 5634560;           // [256*128]
  float* psum   = ws + 5667328;           // [256*128]
  float* fold0  = pmax + 24576;           // [192]
  float* fold1  = psum + 24576;           // [384]
  int*   flag   = (int*)(ws + 5700352);
  int*   idx1   = (int*)(ws + 5700368);   // N*5
  float* nrm    = ws + 5779728;           // N
  float* logits = ws + 5795600;           // UP_ROWS
  float* wcvt   = ws + 6508352;           // 706,020 fp32 weights
  float* S      = ws + 7214400;           // scratch arena (9,662,464 floats)
  ushort_t* whi  = (ushort_t*)(S + 9662464);  // siren fp16 plane (114688)
  ushort_t* wlo  = whi + 114688;
  ushort_t* gwhi = wlo + 114688;              // mlp planes (503808 each)
  ushort_t* gwlo = gwhi + 503808;

  const size_t NEED = (size_t)(7214400 + 9662464) * 4
                    + (size_t)(114688*2 + 503808*2) * 2;   // ~70.0 MB
  if (ws_size < NEED) {
    fillmark_k<<<CDIV(out_size,256),256,0,stream>>>((bf16*)d_out, out_size);
    return;
  }

  // ---- dtype flag + one-shot weight conversion to fp32 ----
  flag_k<<<1,64,0,stream>>>((const uint*)d_in[2], flag);
  CvtTab tab;
  int wcoff = 0, seg = 0;
  auto CVT = [&](int i, int n)->const float* {
    tab.src[seg] = d_in[i]; tab.start[seg] = wcoff; seg++;
    const float* p = wcvt + wcoff; wcoff += n;
    return p;
  };
  const float *E0W1=CVT(4,8960),  *E0S1=CVT(5,128),  *E0H1=CVT(6,128),
              *E0W2=CVT(7,8192),  *E0B2=CVT(8,64);
  const float *F0W1=CVT(9,43584), *F0S1=CVT(10,192), *F0H1=CVT(11,192),
              *F0W2=CVT(12,24576),*F0S2=CVT(13,128), *F0H2=CVT(14,128),
              *F0W3=CVT(15,8192), *F0S3=CVT(16,64),  *F0H3=CVT(17,64),
              *F0W4=CVT(18,4096), *F0B4=CVT(19,64);
  const float *E1W1=CVT(20,32768),*E1S1=CVT(21,256), *E1H1=CVT(22,256),
              *E1W2=CVT(23,32768),*E1B2=CVT(24,128);
  const float *F1W1=CVT(25,172032),*F1S1=CVT(26,384),*F1H1=CVT(27,384),
              *F1W2=CVT(28,98304),*F1S2=CVT(29,256), *F1H2=CVT(30,256),
              *F1W3=CVT(31,32768),*F1S3=CVT(32,128), *F1H3=CVT(33,128),
              *F1W4=CVT(34,16384),*F1B4=CVT(35,128);
  const float *UPW0=CVT(38,896),  *UPS0=CVT(39,128), *UPH0=CVT(40,128),
              *UPWR=CVT(41,114688),*UPSR=CVT(42,896),*UPHR=CVT(43,896),
              *UPWF=CVT(44,128),  *UPBF=CVT(45,1);
  const float *DW0=CVT(46,58112), *DB0=CVT(47,256),
              *DW1=CVT(48,32768), *DB1=CVT(49,128),
              *DW2=CVT(50,8192),  *DB2=CVT(51,64),
              *DW3=CVT(52,2048),  *DB3=CVT(53,32),
              *DW4=CVT(54,512),   *DB4=CVT(55,16),
              *DWF=CVT(56,48),    *DBF=CVT(57,3);
  cvt_all_k<<<CDIV(wcoff,256),256,0,stream>>>(tab, wcvt, flag, wcoff);

  // siren fp16 plane (scale + 1/2pi + sigma folded)
  packfrag16_k<<<CDIV(114688,256),256,0,stream>>>(UPWR, UPSR, whi, 114688);

  // mlp planes in ONE batched launch
  PackTab ptab;
  int offs[18];
  int ptotal = 0;
  {
    int q = 0;
    auto REG = [&](const float* s, int N, int K, int ldk, int Kpad){
      ptab.src[q]=s; ptab.N[q]=N; ptab.K[q]=K; ptab.ldk[q]=ldk; ptab.Kpad[q]=Kpad;
      ptab.start[q]=ptotal; offs[q]=ptotal;
      ptotal += CDIV(N,32)*32*Kpad; q++;
    };
    REG(F0W1,192, 99,227,128);                         // const-folded K
    REG(F0W2,128,192,192,192); REG(F0W3,64,128,128,128); REG(F0W4,64,64,64,64);
    REG(DW0,256,227,227,256);  REG(DW1,128,256,256,256);  REG(DW2,64,128,128,128);
    REG(DW3,32,64,64,64);      REG(DW4,16,32,32,32);      REG(DWF,3,16,16,32);
    REG(E0W1,128,70,70,96);    REG(E0W2,64,128,128,128);
    REG(E1W1,256,128,128,128); REG(E1W2,128,256,256,256);
    REG(F1W3,128,256,256,256); REG(F1W4,128,128,128,128);
    REG(F1W1,384,192,448,192);   // offs[16]: fc1 gemm1 (folded K=192)
    REG(F1W2,256,384,384,384);   // offs[17]: fc1 gemm2
  }
  packw_all_k<<<CDIV(ptotal,256),256,0,stream>>>(ptab, gwhi, gwlo, ptotal);

  auto OFF = [&](const float* p){ return (int)(p - wcvt); };
  const int HOFF0 = (int)(fold0 - wcvt);
  MCfg cfc0{};
  cfc0.L[0] = { 99,192,4,6, offs[0], OFF(F0S1), HOFF0,     0,1, 0.f};
  cfc0.L[1] = {192,128,6,4, offs[1], OFF(F0S2), OFF(F0H2), 0,1, 0.f};
  cfc0.L[2] = {128, 64,4,2, offs[2], OFF(F0S3), OFF(F0H3), 0,1, 0.f};
  cfc0.L[3] = { 64, 64,2,2, offs[3], 0,         OFF(F0B4), 1,0, 0.f};
  MCfg cdec{};
  cdec.L[0] = {227,256,8,8, offs[4], 0, OFF(DB0), 2,2, 30.f};
  cdec.L[1] = {256,128,8,4, offs[5], 0, OFF(DB1), 1,2, 0.f};
  cdec.L[2] = {128, 64,4,2, offs[6], 0, OFF(DB2), 1,2, 0.f};
  cdec.L[3] = { 64, 32,2,1, offs[7], 0, OFF(DB3), 1,2, 0.f};
  cdec.L[4] = { 32, 16,1,1, offs[8], 0, OFF(DB4), 1,2, 0.f};
  cdec.L[5] = { 16,  3,1,1, offs[9], 0, OFF(DBF), 1,0, 0.f};
  MCfg ce0{};
  ce0.L[0] = { 70,128,3,4, offs[10], OFF(E0S1), OFF(E0H1), 0,1, 0.f};
  ce0.L[1] = {128, 64,4,2, offs[11], 0,         OFF(E0B2), 1,0, 0.f};
  MCfg ce1{};
  ce1.L[0] = {128,256,4,8, offs[12], OFF(E1S1), OFF(E1H1), 0,1, 0.f};
  ce1.L[1] = {256,128,8,4, offs[13], 0,         OFF(E1B2), 1,0, 0.f};
  MCfg cf1t{};
  cf1t.L[0] = {256,128,8,4, offs[14], OFF(F1S3), OFF(F1H3), 0,1, 0.f};
  cf1t.L[1] = {128,128,4,4, offs[15], 0,         OFF(F1B4), 1,0, 0.f};

  const float invN = 1.f/(float)N_PTS;

  featin_k<<<CDIV(N_PTS*35,256),256,0,stream>>>(d_in[1], d_in[2], x_feat, flag);

  // ---- phase 1: emb block 0 — fused gather+MLP+kmax (atomicMax into f1b)
  hipMemsetAsync(f1b, 0, (size_t)N_PTS*64*4, stream);
  mlp_edge_k<2><<<CDIV(N_EDGE,64),256,0,stream>>>(
      x_feat, 0, 35, idx0, 0, N_EDGE, ce0, gwhi,gwlo,wcvt, (uint*)f1b, 64);
  reduce1_k<64><<<256,256,0,stream>>>((const uint*)f1b, N_PTS, pmax, psum);
  red2fold_k<64><<<1,256,0,stream>>>(pmax, psum, 256, invN,
                                     F0W1,227, 99,163, F0S1,F0H1, fold0, 192);
  // fc0: varying-only concat (99 ch) then ONE fused MLP
  {
    float* h = S;   // [N,99]
    concat2_k<<<CDIV(N_PTS*99,256),256,0,stream>>>(x_feat,0,35, (const uint*)f1b,64, h, 0, N_PTS);
    mlp_fused_k<4,0><<<CDIV(N_PTS,64),256,0,stream>>>(
        h,99,99,N_PTS, cfc0, gwhi,gwlo,wcvt, x_feat+35,227, nullptr, flag);
  }

  // ---- phase 2: dynamic KNN (MFMA)
  norms_k<<<CDIV(N_PTS,256),256,0,stream>>>(x_feat, nrm);
  {
    const int PLANE = NTILE*5*64*8;
    ushort_t* ajhi = (ushort_t*)S;
    ushort_t* ajlo = ajhi + PLANE;
    ushort_t* bihi = ajlo + PLANE;
    ushort_t* bilo = bihi + PLANE;
    packknn_k<<<CDIV(PLANE,256),256,0,stream>>>(x_feat, nrm, ajhi, ajlo, bihi, bilo);
    knn_mfma_k<<<NTILE,256,0,stream>>>(ajhi, ajlo, bihi, bilo, idx1);
  }

  // ---- phase 3: emb block 1 — fused gather+MLP+kmax, single full-N launch
  hipMemsetAsync(f1b, 0, (size_t)N_PTS*128*4, stream);
  mlp_edge_k<2><<<CDIV(N_EDGE,64),256,0,stream>>>(
      x_feat, 35, 64, idx1, 0, N_EDGE, ce1, gwhi,gwlo,wcvt, (uint*)f1b, 128);
  reduce1_k<128><<<256,256,0,stream>>>((const uint*)f1b, N_PTS, pmax, psum);
  red2fold_k<128><<<1,256,0,stream>>>(pmax, psum, 256, invN,
                                      F1W1,448, 192,320, F1S1,F1H1, fold1, 384);
  // ---- fc1: full-N (no chunking)
  {
    float* h  = S;                   // [N,192]
    float* a1 = S + 3047424;         // [N,384]
    int gx = CDIV(N_PTS,64);         // 248
    concat2_k<<<CDIV(N_PTS*192,256),256,0,stream>>>(x_feat,35,64, (const uint*)f1b,128, h, 0, N_PTS);
    gemm_mfma_k<1><<<dim3(gx,3),256,0,stream>>>(h,192,192,N_PTS, gwhi,gwlo, offs[16],6,
                                                F1S1,fold1, a1,384, 384);
    gemm_mfma_k<1><<<dim3(gx,2),256,0,stream>>>(a1,384,384,N_PTS, gwhi,gwlo, offs[17],12,
                                                F1S2,F1H2, h,256, 256);
    mlp_fused_k<2,0><<<gx,256,0,stream>>>(
        h,256,256,N_PTS, cf1t, gwhi,gwlo,wcvt, x_feat+99,227, nullptr, flag);
  }

  // ---- phase 4: fused SIREN -> logits; softmax gather -> z
  siren_fused_k<<<CDIV(UP_ROWS,128),256,0,stream>>>(
      d_in[36], whi, UPW0, UPS0, UPH0, UPHR, UPWF, UPBF, logits, flag);
  float* zbuf = S;                 // [M,227]
  softgather_k<<<CDIV(M_PTS,4),256,0,stream>>>(logits, upidx, x_feat, zbuf);

  // ---- phase 5: SIREN decoder: ONE fused MLP (incl. 16->3 head + output)
  mlp_fused_k<6,1><<<CDIV(M_PTS,64),256,0,stream>>>(
      zbuf,227,227,M_PTS, cdec, gwhi,gwlo,wcvt, nullptr,0, d_out, flag);
}